// Round 5
// baseline (394.713 us; speedup 1.0000x reference)
//
#include <hip/hip_runtime.h>

#define NNODES 149120
#define NEDGES 2385920
#define NB 64
#define NPMTS 2330
#define HEADK (NPMTS * 3)   // 6990
#define BN_EPS 1e-5f
#define NBLK ((NNODES + 255) / 256)   // 583

#define NBUCK 16
#define BUCKET_N (NNODES / NBUCK)     // 9320 nodes per bucket
#define NCHUNK 512
#define CHUNK_E (NEDGES / NCHUNK)     // 4660 edges per chunk (exact)
#define PACK_SHIFT 14
#define PACK_MASK 16383u
#define DEG_SUB 32                    // sub-blocks per bucket for deg/fill passes

#define HEAD_SEG 4
#define SEGK ((HEADK + HEAD_SEG - 1) / HEAD_SEG)   // 1748

// ================= CSR build: count -> scan -> bin -> deg -> rowstart -> fill =================

// per-(bucket,chunk) histogram, bucket-major layout counts[b*NCHUNK + chunk]
__global__ void k_count(const int* __restrict__ dst, int* __restrict__ counts) {
    __shared__ int c[NBUCK];
    if (threadIdx.x < NBUCK) c[threadIdx.x] = 0;
    __syncthreads();
    int e0 = blockIdx.x * CHUNK_E;
    for (int e = e0 + threadIdx.x; e < e0 + CHUNK_E; e += 256) {
        int d = __builtin_nontemporal_load(&dst[e]);
        atomicAdd(&c[d / BUCKET_N], 1);
    }
    __syncthreads();
    if (threadIdx.x < NBUCK) counts[threadIdx.x * NCHUNK + blockIdx.x] = c[threadIdx.x];
}

// flat exclusive scan of 16*512 = 8192 counts (bucket-major) -> bases; bucket edge offsets -> bstart
__global__ void k_scan8k(const int* __restrict__ counts, int* __restrict__ bases,
                         int* __restrict__ bstart) {
    __shared__ int s[1024];
    int t = threadIdx.x;
    int v[8]; int sum = 0;
#pragma unroll
    for (int i = 0; i < 8; ++i) { v[i] = counts[t * 8 + i]; sum += v[i]; }
    s[t] = sum;
    __syncthreads();
    for (int o = 1; o < 1024; o <<= 1) {
        int x = (t >= o) ? s[t - o] : 0;
        __syncthreads();
        s[t] += x;
        __syncthreads();
    }
    int run = t ? s[t - 1] : 0;   // exclusive base for this thread's 8 elements
#pragma unroll
    for (int i = 0; i < 8; ++i) {
        int idx = t * 8 + i;
        bases[idx] = run;
        if ((idx & (NCHUNK - 1)) == 0) bstart[idx / NCHUNK] = run;
        run += v[i];
    }
    if (t == 0) bstart[NBUCK] = NEDGES;
}

// bin edges into bucket-major packed list; writes are dense per (block,bucket) region
__global__ void k_bin(const int* __restrict__ src, const int* __restrict__ dst,
                      const int* __restrict__ bases, unsigned* __restrict__ packed) {
    __shared__ int base_s[NBUCK];
    __shared__ int cnt[NBUCK];
    if (threadIdx.x < NBUCK) {
        base_s[threadIdx.x] = bases[threadIdx.x * NCHUNK + blockIdx.x];
        cnt[threadIdx.x] = 0;
    }
    __syncthreads();
    int e0 = blockIdx.x * CHUNK_E;
    for (int e = e0 + threadIdx.x; e < e0 + CHUNK_E; e += 256) {
        int d = __builtin_nontemporal_load(&dst[e]);
        int sv = __builtin_nontemporal_load(&src[e]);
        int b = d / BUCKET_N;
        int p = atomicAdd(&cnt[b], 1);
        packed[base_s[b] + p] = ((unsigned)sv << PACK_SHIFT) | (unsigned)(d - b * BUCKET_N);
    }
}

// bucket-local degree count: bucket = blockIdx&15 pins each bucket's deg region to one XCD
__global__ void k_degbin(const unsigned* __restrict__ packed, const int* __restrict__ bstart,
                         int* __restrict__ deg) {
    int b = blockIdx.x & (NBUCK - 1), sub = blockIdx.x >> 4;
    int lo = bstart[b], hi = bstart[b + 1];
    int len = hi - lo;
    int s0 = lo + (int)((long long)len * sub / DEG_SUB);
    int s1 = lo + (int)((long long)len * (sub + 1) / DEG_SUB);
    int nb = b * BUCKET_N;
    for (int e = s0 + threadIdx.x; e < s1; e += 256) {
        unsigned pk = packed[e];
        atomicAdd(&deg[nb + (int)(pk & PACK_MASK)], 1);
    }
}

__global__ void k_blockred(const int* __restrict__ deg, int* __restrict__ bsum) {
    __shared__ int s[256];
    int t = threadIdx.x;
    int n = blockIdx.x * 256 + t;
    s[t] = (n < NNODES) ? deg[n] : 0;
    __syncthreads();
    for (int o = 128; o; o >>= 1) {
        if (t < o) s[t] += s[t + o];
        __syncthreads();
    }
    if (t == 0) bsum[blockIdx.x] = s[0];
}

__global__ void k_bscan(const int* __restrict__ bsum, int* __restrict__ boff) {
    __shared__ int s[1024];
    int t = threadIdx.x;
    s[t] = (t < NBLK) ? bsum[t] : 0;
    __syncthreads();
    for (int o = 1; o < 1024; o <<= 1) {
        int v = (t >= o) ? s[t - o] : 0;
        __syncthreads();
        s[t] += v;
        __syncthreads();
    }
    if (t < NBLK) boff[t] = t ? s[t - 1] : 0;
}

__global__ void k_rowstart(const int* __restrict__ deg, const int* __restrict__ boff,
                           int* __restrict__ rowstart, int* __restrict__ cursor,
                           float* __restrict__ dinv) {
    __shared__ int s[256];
    int t = threadIdx.x;
    int n = blockIdx.x * 256 + t;
    int d = (n < NNODES) ? deg[n] : 0;
    s[t] = d;
    __syncthreads();
    for (int o = 1; o < 256; o <<= 1) {   // inclusive scan
        int v = (t >= o) ? s[t - o] : 0;
        __syncthreads();
        s[t] += v;
        __syncthreads();
    }
    if (n < NNODES) {
        int rs = boff[blockIdx.x] + s[t] - d;   // exclusive
        rowstart[n] = rs;
        cursor[n] = rs;
        dinv[n] = rsqrtf((float)(d + 1));       // +1 self-loop
    }
}

// bucket-local CSR fill: cursor + csr regions for bucket b live in one XCD's L2
__global__ void k_fillbin(const unsigned* __restrict__ packed, const int* __restrict__ bstart,
                          int* __restrict__ cursor, int* __restrict__ csr) {
    int b = blockIdx.x & (NBUCK - 1), sub = blockIdx.x >> 4;
    int lo = bstart[b], hi = bstart[b + 1];
    int len = hi - lo;
    int s0 = lo + (int)((long long)len * sub / DEG_SUB);
    int s1 = lo + (int)((long long)len * (sub + 1) / DEG_SUB);
    int nb = b * BUCKET_N;
    for (int e = s0 + threadIdx.x; e < s1; e += 256) {
        unsigned pk = packed[e];
        int pos = atomicAdd(&cursor[nb + (int)(pk & PACK_MASK)], 1);
        csr[pos] = (int)(pk >> PACK_SHIFT);
    }
}

// ================= GCN layers =================

__global__ void k_pre1(const float* __restrict__ x, const float* __restrict__ dinv,
                       float* __restrict__ xs8) {
    unsigned t = blockIdx.x * blockDim.x + threadIdx.x;
    if (t >= (unsigned)NNODES * 8u) return;
    unsigned n = t >> 3, c = t & 7u;
    xs8[t] = (c < 5u) ? x[n * 5u + c] * dinv[n] : 0.f;
}

__global__ void k_gather8v(const int* __restrict__ rowstart, const int* __restrict__ deg,
                           const int* __restrict__ csr, const float4* __restrict__ xs,
                           float4* __restrict__ agg) {
    unsigned t = blockIdx.x * blockDim.x + threadIdx.x;
    unsigned g = t >> 1, c = t & 1u;
    if (g >= NNODES) return;
    int rs = rowstart[g], d = deg[g];
    float4 acc = xs[g * 2u + c];
    int j = 0;
    for (; j + 4 <= d; j += 4) {
        int s0 = csr[rs + j], s1 = csr[rs + j + 1], s2 = csr[rs + j + 2], s3 = csr[rs + j + 3];
        float4 v0 = xs[(unsigned)s0 * 2u + c], v1 = xs[(unsigned)s1 * 2u + c];
        float4 v2 = xs[(unsigned)s2 * 2u + c], v3 = xs[(unsigned)s3 * 2u + c];
        acc.x += v0.x + v1.x + v2.x + v3.x;
        acc.y += v0.y + v1.y + v2.y + v3.y;
        acc.z += v0.z + v1.z + v2.z + v3.z;
        acc.w += v0.w + v1.w + v2.w + v3.w;
    }
    for (; j < d; ++j) {
        float4 v = xs[(unsigned)csr[rs + j] * 2u + c];
        acc.x += v.x; acc.y += v.y; acc.z += v.z; acc.w += v.w;
    }
    agg[g * 2u + c] = acc;
}

__global__ void k_gather16v(const int* __restrict__ rowstart, const int* __restrict__ deg,
                            const int* __restrict__ csr, const float4* __restrict__ gs,
                            float4* __restrict__ agg) {
    unsigned t = blockIdx.x * blockDim.x + threadIdx.x;
    unsigned g = t >> 2, c = t & 3u;
    if (g >= NNODES) return;
    int rs = rowstart[g], d = deg[g];
    float4 acc = gs[g * 4u + c];
    int j = 0;
    for (; j + 4 <= d; j += 4) {
        int s0 = csr[rs + j], s1 = csr[rs + j + 1], s2 = csr[rs + j + 2], s3 = csr[rs + j + 3];
        float4 v0 = gs[(unsigned)s0 * 4u + c], v1 = gs[(unsigned)s1 * 4u + c];
        float4 v2 = gs[(unsigned)s2 * 4u + c], v3 = gs[(unsigned)s3 * 4u + c];
        acc.x += v0.x + v1.x + v2.x + v3.x;
        acc.y += v0.y + v1.y + v2.y + v3.y;
        acc.z += v0.z + v1.z + v2.z + v3.z;
        acc.w += v0.w + v1.w + v2.w + v3.w;
    }
    for (; j < d; ++j) {
        float4 v = gs[(unsigned)csr[rs + j] * 4u + c];
        acc.x += v.x; acc.y += v.y; acc.z += v.z; acc.w += v.w;
    }
    agg[g * 4u + c] = acc;
}

__global__ void k_gather4_final(const int* __restrict__ rowstart, const int* __restrict__ deg,
                                const int* __restrict__ csr, const float4* __restrict__ g3,
                                const float* __restrict__ dinv, const float* __restrict__ b3,
                                float* __restrict__ h3) {
    unsigned g = blockIdx.x * blockDim.x + threadIdx.x;
    if (g >= NNODES) return;
    int rs = rowstart[g], d = deg[g];
    float4 acc = g3[g];
    int j = 0;
    for (; j + 4 <= d; j += 4) {
        int s0 = csr[rs + j], s1 = csr[rs + j + 1], s2 = csr[rs + j + 2], s3 = csr[rs + j + 3];
        float4 v0 = g3[s0], v1 = g3[s1], v2 = g3[s2], v3 = g3[s3];
        acc.x += v0.x + v1.x + v2.x + v3.x;
        acc.y += v0.y + v1.y + v2.y + v3.y;
        acc.z += v0.z + v1.z + v2.z + v3.z;
    }
    for (; j < d; ++j) {
        float4 v = g3[csr[rs + j]];
        acc.x += v.x; acc.y += v.y; acc.z += v.z;
    }
    float di = dinv[g];
    float o0 = acc.x * di + b3[0];
    float o1 = acc.y * di + b3[1];
    float o2 = acc.z * di + b3[2];
    h3[g * 3u + 0] = o0 > 0.f ? o0 : 0.f;
    h3[g * 3u + 1] = o1 > 0.f ? o1 : 0.f;
    h3[g * 3u + 2] = o2 > 0.f ? o2 : 0.f;
}

__global__ void k_mm12(const float* __restrict__ agg8, const float* __restrict__ dinv,
                       const float* __restrict__ W1, const float* __restrict__ b1,
                       const float* __restrict__ W2, float* __restrict__ g2s) {
    __shared__ float W1s[5 * 32], W2s[32 * 16], b1s[32];
    int tid = threadIdx.x;  // 256
    if (tid < 5 * 32) W1s[tid] = W1[tid];
    if (tid < 32) b1s[tid] = b1[tid];
    for (int i = tid; i < 32 * 16; i += 256) W2s[i] = W2[i];
    __syncthreads();

    unsigned n = blockIdx.x * blockDim.x + tid;
    if (n >= NNODES) return;
    float di = dinv[n];
    float a[5];
#pragma unroll
    for (int k = 0; k < 5; ++k) a[k] = agg8[n * 8u + k] * di;

    float h[32];
#pragma unroll
    for (int j = 0; j < 32; ++j) {
        float acc = b1s[j];
#pragma unroll
        for (int k = 0; k < 5; ++k) acc += a[k] * W1s[k * 32 + j];
        h[j] = acc > 0.f ? acc : 0.f;
    }
    float g[16];
#pragma unroll
    for (int c = 0; c < 16; ++c) g[c] = 0.f;
#pragma unroll
    for (int j = 0; j < 32; ++j) {
        float hj = h[j];
#pragma unroll
        for (int c = 0; c < 16; ++c) g[c] += hj * W2s[j * 16 + c];
    }
#pragma unroll
    for (int c = 0; c < 16; ++c) g2s[n * 16u + c] = g[c] * di;
}

__global__ void k_mm3(const float* __restrict__ agg2, const float* __restrict__ dinv,
                      const float* __restrict__ b2, const float* __restrict__ W3,
                      float* __restrict__ g3s4) {
    __shared__ float W3s[16 * 3], b2s[16];
    int tid = threadIdx.x;
    if (tid < 16 * 3) W3s[tid] = W3[tid];
    if (tid < 16) b2s[tid] = b2[tid];
    __syncthreads();

    unsigned n = blockIdx.x * blockDim.x + tid;
    if (n >= NNODES) return;
    float di = dinv[n];
    float t2[16];
#pragma unroll
    for (int j = 0; j < 16; ++j) {
        float v = agg2[n * 16u + j] * di + b2s[j];
        t2[j] = v > 0.f ? v : 0.f;
    }
    float g[3] = {0.f, 0.f, 0.f};
#pragma unroll
    for (int j = 0; j < 16; ++j) {
        float tj = t2[j];
#pragma unroll
        for (int c = 0; c < 3; ++c) g[c] += tj * W3s[j * 3 + c];
    }
#pragma unroll
    for (int c = 0; c < 3; ++c) g3s4[n * 4u + c] = g[c] * di;
    g3s4[n * 4u + 3] = 0.f;
}

// ================= head =================

__global__ void k_head2(const float* __restrict__ h3, const float* __restrict__ Wl1,
                        float* __restrict__ zpart) {
    __shared__ float hrow[SEGK];
    __shared__ float part[8][32];
    int b = blockIdx.x >> 2, seg = blockIdx.x & 3;
    int k0 = seg * SEGK;
    int kend = k0 + SEGK; if (kend > HEADK) kend = HEADK;
    int cnt = kend - k0;
    for (int k = threadIdx.x; k < cnt; k += 256) hrow[k] = h3[b * HEADK + k0 + k];
    __syncthreads();
    int j = threadIdx.x & 31, g = threadIdx.x >> 5;
    float acc = 0.f;
    for (int k = g; k < cnt; k += 8) acc += hrow[k] * Wl1[(k0 + k) * 32 + j];
    part[g][j] = acc;
    __syncthreads();
    if (threadIdx.x < 32) {
        float s = 0.f;
#pragma unroll
        for (int g2 = 0; g2 < 8; ++g2) s += part[g2][j];
        zpart[(seg * NB + b) * 32 + j] = s;
    }
}

__global__ void k_bn_final(const float* __restrict__ zpart, const float* __restrict__ bl1,
                           const float* __restrict__ gamma, const float* __restrict__ beta,
                           const float* __restrict__ Wl2, const float* __restrict__ bl2,
                           float* __restrict__ out) {
    __shared__ float zs[NB][32];
    __shared__ float scale[32], shift[32];
    int tid = threadIdx.x;  // 256
    for (int i = tid; i < NB * 32; i += 256) {
        float v = bl1[i & 31];
#pragma unroll
        for (int sgm = 0; sgm < 4; ++sgm) v += zpart[sgm * NB * 32 + i];
        zs[i >> 5][i & 31] = v;
    }
    __syncthreads();
    if (tid < 32) {
        float m = 0.f, v = 0.f;
        for (int b = 0; b < NB; ++b) { float xv = zs[b][tid]; m += xv; v += xv * xv; }
        m /= (float)NB;
        v = v / (float)NB - m * m;
        float sc = gamma[tid] * rsqrtf(v + BN_EPS);
        scale[tid] = sc;
        shift[tid] = beta[tid] - m * sc;
    }
    __syncthreads();
    if (tid < NB) {
        float acc = bl2[0];
#pragma unroll
        for (int j = 0; j < 32; ++j) {
            float zv = zs[tid][j] * scale[j] + shift[j];
            zv = zv > 0.f ? zv : 0.f;
            acc += zv * Wl2[j];
        }
        out[tid] = acc;
    }
}

// ================= launch =================

extern "C" void kernel_launch(void* const* d_in, const int* in_sizes, int n_in,
                              void* d_out, int out_size, void* d_ws, size_t ws_size,
                              hipStream_t stream) {
    const float* x    = (const float*)d_in[0];
    const int*   ei   = (const int*)d_in[1];
    const float* W1   = (const float*)d_in[2];
    const float* b1   = (const float*)d_in[3];
    const float* W2   = (const float*)d_in[4];
    const float* b2   = (const float*)d_in[5];
    const float* W3   = (const float*)d_in[6];
    const float* b3   = (const float*)d_in[7];
    const float* Wl1  = (const float*)d_in[8];
    const float* bl1  = (const float*)d_in[9];
    const float* gamma= (const float*)d_in[10];
    const float* beta = (const float*)d_in[11];
    const float* Wl2  = (const float*)d_in[12];
    const float* bl2  = (const float*)d_in[13];

    const int* src = ei;            // edge_index[0]
    const int* dst = ei + NEDGES;   // edge_index[1]

    char* ws = (char*)d_ws;
    size_t off = 0;
    float*    dinv     = (float*)   (ws + off); off += (size_t)NNODES * 4;
    int*      deg      = (int*)     (ws + off); off += (size_t)NNODES * 4;
    int*      bsum     = (int*)     (ws + off); off += (size_t)1024 * 4;
    int*      boff     = (int*)     (ws + off); off += (size_t)1024 * 4;
    int*      counts   = (int*)     (ws + off); off += (size_t)NBUCK * NCHUNK * 4;
    int*      bases    = (int*)     (ws + off); off += (size_t)NBUCK * NCHUNK * 4;
    int*      bstart   = (int*)     (ws + off); off += (size_t)(NBUCK + 1) * 4;
    off = (off + 255) & ~(size_t)255;
    unsigned* packed   = (unsigned*)(ws + off); off += (size_t)NEDGES * 4;
    int*      rowstart = (int*)     (ws + off); off += (size_t)NNODES * 4;
    int*      cursor   = (int*)     (ws + off); off += (size_t)NNODES * 4;
    int*      csr      = (int*)     (ws + off); off += (size_t)NEDGES * 4;
    float*    xs8      = (float*)   (ws + off); off += (size_t)NNODES * 8 * 4;
    float*    agg8     = (float*)   (ws + off); off += (size_t)NNODES * 8 * 4;
    float*    g2s      = (float*)   (ws + off); off += (size_t)NNODES * 16 * 4;
    float*    agg2     = (float*)   (ws + off); off += (size_t)NNODES * 16 * 4;
    float*    g3s4     = (float*)   (ws + off); off += (size_t)NNODES * 4 * 4;
    float*    h3       = (float*)   (ws + off); off += (size_t)NNODES * 3 * 4;
    float*    zpart    = (float*)   (ws + off); off += (size_t)4 * NB * 32 * 4;

    float* outp = (float*)d_out;

    // ---- CSR build via bucket-major counting sort (all scattered ops bucket-local)
    hipMemsetAsync(deg, 0, (size_t)NNODES * 4, stream);
    k_count<<<NCHUNK, 256, 0, stream>>>(dst, counts);
    k_scan8k<<<1, 1024, 0, stream>>>(counts, bases, bstart);
    k_bin<<<NCHUNK, 256, 0, stream>>>(src, dst, bases, packed);
    k_degbin<<<NBUCK * DEG_SUB, 256, 0, stream>>>(packed, bstart, deg);
    k_blockred<<<NBLK, 256, 0, stream>>>(deg, bsum);
    k_bscan<<<1, 1024, 0, stream>>>(bsum, boff);
    k_rowstart<<<NBLK, 256, 0, stream>>>(deg, boff, rowstart, cursor, dinv);
    k_fillbin<<<NBUCK * DEG_SUB, 256, 0, stream>>>(packed, bstart, cursor, csr);

    // ---- layer 1: aggregate in 5-dim (padded 8) input space, gather-based
    k_pre1<<<(int)(((unsigned)NNODES * 8u + 255) / 256), 256, 0, stream>>>(x, dinv, xs8);
    k_gather8v<<<(int)(((unsigned)NNODES * 2u + 255) / 256), 256, 0, stream>>>(
        rowstart, deg, csr, (const float4*)xs8, (float4*)agg8);

    // ---- fused mm1 + relu + mm2 + prescale
    k_mm12<<<(NNODES + 255) / 256, 256, 0, stream>>>(agg8, dinv, W1, b1, W2, g2s);
    k_gather16v<<<(int)(((unsigned)NNODES * 4u + 255) / 256), 256, 0, stream>>>(
        rowstart, deg, csr, (const float4*)g2s, (float4*)agg2);

    // ---- fused relu(layer2) + mm3 + prescale
    k_mm3<<<(NNODES + 255) / 256, 256, 0, stream>>>(agg2, dinv, b2, W3, g3s4);
    k_gather4_final<<<(NNODES + 255) / 256, 256, 0, stream>>>(
        rowstart, deg, csr, (const float4*)g3s4, dinv, b3, h3);

    // ---- head + BN + final linear
    k_head2<<<NB * HEAD_SEG, 256, 0, stream>>>(h3, Wl1, zpart);
    k_bn_final<<<1, 256, 0, stream>>>(zpart, bl1, gamma, beta, Wl2, bl2, outp);
}

// Round 6
// 292.927 us; speedup vs baseline: 1.3475x; 1.3475x over previous
//
#include <hip/hip_runtime.h>

#define NNODES 149120
#define NEDGES 2385920
#define NB 64
#define NPMTS 2330
#define HEADK (NPMTS * 3)   // 6990
#define BN_EPS 1e-5f

#define NBUCK 256
#define BUCKET_N 583                    // 256*583 = 149248 >= NNODES
#define NCHUNK 256
#define CHUNK_E (NEDGES / NCHUNK)       // 9320 (exact)
#define FPACK_SHIFT 10
#define FPACK_MASK 1023u
#define CAP 10240                       // max edges per bucket (mean 9329, sigma 97)

#define HEAD_SEG 4
#define SEGK ((HEADK + HEAD_SEG - 1) / HEAD_SEG)   // 1748

// ================= CSR build: count -> scan -> LDS-sorted bin -> per-bucket build =================

__global__ void k_count(const int* __restrict__ dst, int* __restrict__ counts) {
    __shared__ int c[NBUCK];
    for (int i = threadIdx.x; i < NBUCK; i += 256) c[i] = 0;
    __syncthreads();
    int e0 = blockIdx.x * CHUNK_E;
    for (int e = e0 + threadIdx.x; e < e0 + CHUNK_E; e += 256) {
        int d = __builtin_nontemporal_load(&dst[e]);
        atomicAdd(&c[d / BUCKET_N], 1);
    }
    __syncthreads();
    for (int i = threadIdx.x; i < NBUCK; i += 256) counts[i * NCHUNK + blockIdx.x] = c[i];
}

// exclusive scan of all 65536 counts (bucket-major); bstart[b] = scan at (b, chunk 0)
__global__ void k_scan64k(const int* __restrict__ counts, int* __restrict__ bases,
                          int* __restrict__ bstart) {
    __shared__ int s[1024];
    int t = threadIdx.x;
    int base_i = t * 64;
    int sum = 0;
    for (int i = 0; i < 64; ++i) sum += counts[base_i + i];
    s[t] = sum;
    __syncthreads();
    for (int o = 1; o < 1024; o <<= 1) {
        int x = (t >= o) ? s[t - o] : 0;
        __syncthreads();
        s[t] += x;
        __syncthreads();
    }
    int run = t ? s[t - 1] : 0;
    for (int i = 0; i < 64; ++i) {
        int idx = base_i + i;
        int cv = counts[idx];
        bases[idx] = run;
        if ((idx & (NCHUNK - 1)) == 0) bstart[idx >> 8] = run;
        run += cv;
    }
    if (t == 0) bstart[NBUCK] = NEDGES;
}

// per-chunk LDS counting sort by bucket, then coalesced run-writes into packed
__global__ __launch_bounds__(256) void k_bin_sorted(const int* __restrict__ src,
                                                    const int* __restrict__ dst,
                                                    const int* __restrict__ bases,
                                                    unsigned* __restrict__ packed) {
    __shared__ unsigned ds[CHUNK_E];     // 37.3 KB
    __shared__ unsigned outp[CHUNK_E];   // 37.3 KB
    __shared__ int hist[NBUCK];          // doubles as cursor
    __shared__ int basel[NBUCK + 1];
    __shared__ int gbase[NBUCK];
    __shared__ int tmp[NBUCK];
    int t = threadIdx.x;
    int e0 = blockIdx.x * CHUNK_E;
    hist[t] = 0;
    gbase[t] = bases[t * NCHUNK + blockIdx.x];
    __syncthreads();
    for (int i = t; i < CHUNK_E; i += 256) {
        int d = __builtin_nontemporal_load(&dst[e0 + i]);
        ds[i] = (unsigned)d;
        atomicAdd(&hist[d / BUCKET_N], 1);
    }
    __syncthreads();
    int hv = hist[t];
    tmp[t] = hv;
    __syncthreads();
    for (int o = 1; o < 256; o <<= 1) {
        int x = (t >= o) ? tmp[t - o] : 0;
        __syncthreads();
        tmp[t] += x;
        __syncthreads();
    }
    basel[t] = tmp[t] - hv;   // exclusive
    if (t == 255) basel[256] = tmp[255];
    hist[t] = tmp[t] - hv;    // cursor
    __syncthreads();
    for (int i = t; i < CHUNK_E; i += 256) {
        unsigned d = ds[i];
        unsigned b = d / BUCKET_N;
        int sv = __builtin_nontemporal_load(&src[e0 + i]);
        int pos = atomicAdd(&hist[b], 1);
        outp[pos] = ((unsigned)sv << FPACK_SHIFT) | (d - b * BUCKET_N);
    }
    __syncthreads();
    for (int i = t; i < CHUNK_E; i += 256) {
        int lo = 0, hi = NBUCK;   // find b: basel[b] <= i < basel[b+1]
        while (lo + 1 < hi) {
            int mid = (lo + hi) >> 1;
            if (basel[mid] <= i) lo = mid; else hi = mid;
        }
        packed[gbase[lo] + (i - basel[lo])] = outp[i];
    }
}

// one block per bucket: LDS degree hist -> scan -> scatter -> coalesced writes of deg/rowstart/dinv/csr
__global__ __launch_bounds__(256) void k_build(const unsigned* __restrict__ packed,
                                               const int* __restrict__ bstart,
                                               int* __restrict__ deg, int* __restrict__ rowstart,
                                               float* __restrict__ dinv, int* __restrict__ csr) {
    __shared__ unsigned pk[CAP];   // 40 KB
    __shared__ int csr_l[CAP];     // 40 KB
    __shared__ int ldeg[768];
    __shared__ int lrow[768];
    __shared__ int part[256];
    int t = threadIdx.x;
    int b = blockIdx.x;
    int lo = bstart[b], hi = bstart[b + 1];
    int len = hi - lo;
    if (len > CAP) len = CAP;
    for (int i = t; i < len; i += 256) pk[i] = packed[lo + i];
    for (int i = t; i < 768; i += 256) ldeg[i] = 0;
    __syncthreads();
    for (int i = t; i < len; i += 256) atomicAdd(&ldeg[pk[i] & FPACK_MASK], 1);
    __syncthreads();
    int a0 = ldeg[t * 3], a1 = ldeg[t * 3 + 1], a2 = ldeg[t * 3 + 2];
    part[t] = a0 + a1 + a2;
    __syncthreads();
    for (int o = 1; o < 256; o <<= 1) {
        int x = (t >= o) ? part[t - o] : 0;
        __syncthreads();
        part[t] += x;
        __syncthreads();
    }
    int run = t ? part[t - 1] : 0;
    lrow[t * 3] = run;
    lrow[t * 3 + 1] = run + a0;
    lrow[t * 3 + 2] = run + a0 + a1;
    __syncthreads();
    int n0 = b * BUCKET_N;
    int nnode = NNODES - n0; if (nnode > BUCKET_N) nnode = BUCKET_N;
    for (int l = t; l < nnode; l += 256) {
        int dg = ldeg[l];
        deg[n0 + l] = dg;
        rowstart[n0 + l] = lo + lrow[l];
        dinv[n0 + l] = rsqrtf((float)(dg + 1));
    }
    for (int l = t; l < 768; l += 256) ldeg[l] = lrow[l];   // cursor
    __syncthreads();
    for (int i = t; i < len; i += 256) {
        unsigned v = pk[i];
        int pos = atomicAdd(&ldeg[v & FPACK_MASK], 1);
        csr_l[pos] = (int)(v >> FPACK_SHIFT);
    }
    __syncthreads();
    for (int i = t; i < len; i += 256) csr[lo + i] = csr_l[i];
}

// ================= GCN layers =================

__global__ void k_pre1(const float* __restrict__ x, const float* __restrict__ dinv,
                       float* __restrict__ xs8) {
    unsigned t = blockIdx.x * blockDim.x + threadIdx.x;
    if (t >= (unsigned)NNODES * 8u) return;
    unsigned n = t >> 3, c = t & 7u;
    xs8[t] = (c < 5u) ? x[n * 5u + c] * dinv[n] : 0.f;
}

__global__ void k_gather8v(const int* __restrict__ rowstart, const int* __restrict__ deg,
                           const int* __restrict__ csr, const float4* __restrict__ xs,
                           float4* __restrict__ agg) {
    unsigned t = blockIdx.x * blockDim.x + threadIdx.x;
    unsigned g = t >> 1, c = t & 1u;
    if (g >= NNODES) return;
    int rs = rowstart[g], d = deg[g];
    float4 acc = xs[g * 2u + c];
    int j = 0;
    for (; j + 4 <= d; j += 4) {
        int s0 = csr[rs + j], s1 = csr[rs + j + 1], s2 = csr[rs + j + 2], s3 = csr[rs + j + 3];
        float4 v0 = xs[(unsigned)s0 * 2u + c], v1 = xs[(unsigned)s1 * 2u + c];
        float4 v2 = xs[(unsigned)s2 * 2u + c], v3 = xs[(unsigned)s3 * 2u + c];
        acc.x += v0.x + v1.x + v2.x + v3.x;
        acc.y += v0.y + v1.y + v2.y + v3.y;
        acc.z += v0.z + v1.z + v2.z + v3.z;
        acc.w += v0.w + v1.w + v2.w + v3.w;
    }
    for (; j < d; ++j) {
        float4 v = xs[(unsigned)csr[rs + j] * 2u + c];
        acc.x += v.x; acc.y += v.y; acc.z += v.z; acc.w += v.w;
    }
    agg[g * 2u + c] = acc;
}

__global__ void k_gather16v(const int* __restrict__ rowstart, const int* __restrict__ deg,
                            const int* __restrict__ csr, const float4* __restrict__ gs,
                            float4* __restrict__ agg) {
    unsigned t = blockIdx.x * blockDim.x + threadIdx.x;
    unsigned g = t >> 2, c = t & 3u;
    if (g >= NNODES) return;
    int rs = rowstart[g], d = deg[g];
    float4 acc = gs[g * 4u + c];
    int j = 0;
    for (; j + 4 <= d; j += 4) {
        int s0 = csr[rs + j], s1 = csr[rs + j + 1], s2 = csr[rs + j + 2], s3 = csr[rs + j + 3];
        float4 v0 = gs[(unsigned)s0 * 4u + c], v1 = gs[(unsigned)s1 * 4u + c];
        float4 v2 = gs[(unsigned)s2 * 4u + c], v3 = gs[(unsigned)s3 * 4u + c];
        acc.x += v0.x + v1.x + v2.x + v3.x;
        acc.y += v0.y + v1.y + v2.y + v3.y;
        acc.z += v0.z + v1.z + v2.z + v3.z;
        acc.w += v0.w + v1.w + v2.w + v3.w;
    }
    for (; j < d; ++j) {
        float4 v = gs[(unsigned)csr[rs + j] * 4u + c];
        acc.x += v.x; acc.y += v.y; acc.z += v.z; acc.w += v.w;
    }
    agg[g * 4u + c] = acc;
}

__global__ void k_gather4_final(const int* __restrict__ rowstart, const int* __restrict__ deg,
                                const int* __restrict__ csr, const float4* __restrict__ g3,
                                const float* __restrict__ dinv, const float* __restrict__ b3,
                                float* __restrict__ h3) {
    unsigned g = blockIdx.x * blockDim.x + threadIdx.x;
    if (g >= NNODES) return;
    int rs = rowstart[g], d = deg[g];
    float4 acc = g3[g];
    int j = 0;
    for (; j + 4 <= d; j += 4) {
        int s0 = csr[rs + j], s1 = csr[rs + j + 1], s2 = csr[rs + j + 2], s3 = csr[rs + j + 3];
        float4 v0 = g3[s0], v1 = g3[s1], v2 = g3[s2], v3 = g3[s3];
        acc.x += v0.x + v1.x + v2.x + v3.x;
        acc.y += v0.y + v1.y + v2.y + v3.y;
        acc.z += v0.z + v1.z + v2.z + v3.z;
    }
    for (; j < d; ++j) {
        float4 v = g3[csr[rs + j]];
        acc.x += v.x; acc.y += v.y; acc.z += v.z;
    }
    float di = dinv[g];
    float o0 = acc.x * di + b3[0];
    float o1 = acc.y * di + b3[1];
    float o2 = acc.z * di + b3[2];
    h3[g * 3u + 0] = o0 > 0.f ? o0 : 0.f;
    h3[g * 3u + 1] = o1 > 0.f ? o1 : 0.f;
    h3[g * 3u + 2] = o2 > 0.f ? o2 : 0.f;
}

__global__ void k_mm12(const float* __restrict__ agg8, const float* __restrict__ dinv,
                       const float* __restrict__ W1, const float* __restrict__ b1,
                       const float* __restrict__ W2, float* __restrict__ g2s) {
    __shared__ float W1s[5 * 32], W2s[32 * 16], b1s[32];
    int tid = threadIdx.x;  // 256
    if (tid < 5 * 32) W1s[tid] = W1[tid];
    if (tid < 32) b1s[tid] = b1[tid];
    for (int i = tid; i < 32 * 16; i += 256) W2s[i] = W2[i];
    __syncthreads();

    unsigned n = blockIdx.x * blockDim.x + tid;
    if (n >= NNODES) return;
    float di = dinv[n];
    float a[5];
#pragma unroll
    for (int k = 0; k < 5; ++k) a[k] = agg8[n * 8u + k] * di;

    float h[32];
#pragma unroll
    for (int j = 0; j < 32; ++j) {
        float acc = b1s[j];
#pragma unroll
        for (int k = 0; k < 5; ++k) acc += a[k] * W1s[k * 32 + j];
        h[j] = acc > 0.f ? acc : 0.f;
    }
    float g[16];
#pragma unroll
    for (int c = 0; c < 16; ++c) g[c] = 0.f;
#pragma unroll
    for (int j = 0; j < 32; ++j) {
        float hj = h[j];
#pragma unroll
        for (int c = 0; c < 16; ++c) g[c] += hj * W2s[j * 16 + c];
    }
#pragma unroll
    for (int c = 0; c < 16; ++c) g2s[n * 16u + c] = g[c] * di;
}

__global__ void k_mm3(const float* __restrict__ agg2, const float* __restrict__ dinv,
                      const float* __restrict__ b2, const float* __restrict__ W3,
                      float* __restrict__ g3s4) {
    __shared__ float W3s[16 * 3], b2s[16];
    int tid = threadIdx.x;
    if (tid < 16 * 3) W3s[tid] = W3[tid];
    if (tid < 16) b2s[tid] = b2[tid];
    __syncthreads();

    unsigned n = blockIdx.x * blockDim.x + tid;
    if (n >= NNODES) return;
    float di = dinv[n];
    float t2[16];
#pragma unroll
    for (int j = 0; j < 16; ++j) {
        float v = agg2[n * 16u + j] * di + b2s[j];
        t2[j] = v > 0.f ? v : 0.f;
    }
    float g[3] = {0.f, 0.f, 0.f};
#pragma unroll
    for (int j = 0; j < 16; ++j) {
        float tj = t2[j];
#pragma unroll
        for (int c = 0; c < 3; ++c) g[c] += tj * W3s[j * 3 + c];
    }
#pragma unroll
    for (int c = 0; c < 3; ++c) g3s4[n * 4u + c] = g[c] * di;
    g3s4[n * 4u + 3] = 0.f;
}

// ================= head =================

__global__ void k_head2(const float* __restrict__ h3, const float* __restrict__ Wl1,
                        float* __restrict__ zpart) {
    __shared__ float hrow[SEGK];
    __shared__ float part[8][32];
    int b = blockIdx.x >> 2, seg = blockIdx.x & 3;
    int k0 = seg * SEGK;
    int kend = k0 + SEGK; if (kend > HEADK) kend = HEADK;
    int cnt = kend - k0;
    for (int k = threadIdx.x; k < cnt; k += 256) hrow[k] = h3[b * HEADK + k0 + k];
    __syncthreads();
    int j = threadIdx.x & 31, g = threadIdx.x >> 5;
    float acc = 0.f;
    for (int k = g; k < cnt; k += 8) acc += hrow[k] * Wl1[(k0 + k) * 32 + j];
    part[g][j] = acc;
    __syncthreads();
    if (threadIdx.x < 32) {
        float s = 0.f;
#pragma unroll
        for (int g2 = 0; g2 < 8; ++g2) s += part[g2][j];
        zpart[(seg * NB + b) * 32 + j] = s;
    }
}

__global__ void k_bn_final(const float* __restrict__ zpart, const float* __restrict__ bl1,
                           const float* __restrict__ gamma, const float* __restrict__ beta,
                           const float* __restrict__ Wl2, const float* __restrict__ bl2,
                           float* __restrict__ out) {
    __shared__ float zs[NB][32];
    __shared__ float scale[32], shift[32];
    int tid = threadIdx.x;  // 256
    for (int i = tid; i < NB * 32; i += 256) {
        float v = bl1[i & 31];
#pragma unroll
        for (int sgm = 0; sgm < 4; ++sgm) v += zpart[sgm * NB * 32 + i];
        zs[i >> 5][i & 31] = v;
    }
    __syncthreads();
    if (tid < 32) {
        float m = 0.f, v = 0.f;
        for (int b = 0; b < NB; ++b) { float xv = zs[b][tid]; m += xv; v += xv * xv; }
        m /= (float)NB;
        v = v / (float)NB - m * m;
        float sc = gamma[tid] * rsqrtf(v + BN_EPS);
        scale[tid] = sc;
        shift[tid] = beta[tid] - m * sc;
    }
    __syncthreads();
    if (tid < NB) {
        float acc = bl2[0];
#pragma unroll
        for (int j = 0; j < 32; ++j) {
            float zv = zs[tid][j] * scale[j] + shift[j];
            zv = zv > 0.f ? zv : 0.f;
            acc += zv * Wl2[j];
        }
        out[tid] = acc;
    }
}

// ================= launch =================

extern "C" void kernel_launch(void* const* d_in, const int* in_sizes, int n_in,
                              void* d_out, int out_size, void* d_ws, size_t ws_size,
                              hipStream_t stream) {
    const float* x    = (const float*)d_in[0];
    const int*   ei   = (const int*)d_in[1];
    const float* W1   = (const float*)d_in[2];
    const float* b1   = (const float*)d_in[3];
    const float* W2   = (const float*)d_in[4];
    const float* b2   = (const float*)d_in[5];
    const float* W3   = (const float*)d_in[6];
    const float* b3   = (const float*)d_in[7];
    const float* Wl1  = (const float*)d_in[8];
    const float* bl1  = (const float*)d_in[9];
    const float* gamma= (const float*)d_in[10];
    const float* beta = (const float*)d_in[11];
    const float* Wl2  = (const float*)d_in[12];
    const float* bl2  = (const float*)d_in[13];

    const int* src = ei;            // edge_index[0]
    const int* dst = ei + NEDGES;   // edge_index[1]

    char* ws = (char*)d_ws;
    size_t off = 0;
    float*    dinv     = (float*)   (ws + off); off += (size_t)NNODES * 4;
    int*      deg      = (int*)     (ws + off); off += (size_t)NNODES * 4;
    int*      counts   = (int*)     (ws + off); off += (size_t)NBUCK * NCHUNK * 4;
    int*      bases    = (int*)     (ws + off); off += (size_t)NBUCK * NCHUNK * 4;
    int*      bstart   = (int*)     (ws + off); off += (size_t)(NBUCK + 1) * 4;
    off = (off + 255) & ~(size_t)255;
    unsigned* packed   = (unsigned*)(ws + off); off += (size_t)NEDGES * 4;
    int*      rowstart = (int*)     (ws + off); off += (size_t)NNODES * 4;
    int*      csr      = (int*)     (ws + off); off += (size_t)NEDGES * 4;
    float*    xs8      = (float*)   (ws + off); off += (size_t)NNODES * 8 * 4;
    float*    agg8     = (float*)   (ws + off); off += (size_t)NNODES * 8 * 4;
    float*    g2s      = (float*)   (ws + off); off += (size_t)NNODES * 16 * 4;
    float*    agg2     = (float*)   (ws + off); off += (size_t)NNODES * 16 * 4;
    float*    g3s4     = (float*)   (ws + off); off += (size_t)NNODES * 4 * 4;
    float*    h3       = (float*)   (ws + off); off += (size_t)NNODES * 3 * 4;
    float*    zpart    = (float*)   (ws + off); off += (size_t)4 * NB * 32 * 4;

    float* outp = (float*)d_out;

    // ---- CSR build: all scattered stores staged through LDS, all global stores coalesced
    k_count<<<NCHUNK, 256, 0, stream>>>(dst, counts);
    k_scan64k<<<1, 1024, 0, stream>>>(counts, bases, bstart);
    k_bin_sorted<<<NCHUNK, 256, 0, stream>>>(src, dst, bases, packed);
    k_build<<<NBUCK, 256, 0, stream>>>(packed, bstart, deg, rowstart, dinv, csr);

    // ---- layer 1: aggregate in 5-dim (padded 8) input space, gather-based
    k_pre1<<<(int)(((unsigned)NNODES * 8u + 255) / 256), 256, 0, stream>>>(x, dinv, xs8);
    k_gather8v<<<(int)(((unsigned)NNODES * 2u + 255) / 256), 256, 0, stream>>>(
        rowstart, deg, csr, (const float4*)xs8, (float4*)agg8);

    // ---- fused mm1 + relu + mm2 + prescale
    k_mm12<<<(NNODES + 255) / 256, 256, 0, stream>>>(agg8, dinv, W1, b1, W2, g2s);
    k_gather16v<<<(int)(((unsigned)NNODES * 4u + 255) / 256), 256, 0, stream>>>(
        rowstart, deg, csr, (const float4*)g2s, (float4*)agg2);

    // ---- fused relu(layer2) + mm3 + prescale
    k_mm3<<<(NNODES + 255) / 256, 256, 0, stream>>>(agg2, dinv, b2, W3, g3s4);
    k_gather4_final<<<(NNODES + 255) / 256, 256, 0, stream>>>(
        rowstart, deg, csr, (const float4*)g3s4, dinv, b3, h3);

    // ---- head + BN + final linear
    k_head2<<<NB * HEAD_SEG, 256, 0, stream>>>(h3, Wl1, zpart);
    k_bn_final<<<1, 256, 0, stream>>>(zpart, bl1, gamma, beta, Wl2, bl2, outp);
}

// Round 7
// 245.066 us; speedup vs baseline: 1.6106x; 1.1953x over previous
//
#include <hip/hip_runtime.h>

#define NNODES 149120
#define NEDGES 2385920
#define NB 64
#define NPMTS 2330
#define HEADK (NPMTS * 3)   // 6990
#define BN_EPS 1e-5f

#define NBUCK 256
#define BUCKET_N 583                    // 256*583 = 149248 >= NNODES
#define NCHUNK 256
#define CHUNK_E (NEDGES / NCHUNK)       // 9320 (exact)
#define FPACK_SHIFT 10
#define FPACK_MASK 1023u
#define CAP 10240                       // max edges per bucket (mean 9329, sigma 97)

#define HEAD_SEG 32
#define SEGK ((HEADK + HEAD_SEG - 1) / HEAD_SEG)   // 219

// ================= CSR build: count -> scan -> LDS-sorted bin -> per-bucket build =================

__global__ void k_count(const int* __restrict__ dst, int* __restrict__ counts) {
    __shared__ int c[NBUCK];
    for (int i = threadIdx.x; i < NBUCK; i += 256) c[i] = 0;
    __syncthreads();
    int e0 = blockIdx.x * CHUNK_E;
    for (int e = e0 + threadIdx.x; e < e0 + CHUNK_E; e += 256) {
        int d = __builtin_nontemporal_load(&dst[e]);
        atomicAdd(&c[d / BUCKET_N], 1);
    }
    __syncthreads();
    for (int i = threadIdx.x; i < NBUCK; i += 256) counts[i * NCHUNK + blockIdx.x] = c[i];
}

// exclusive scan of all 65536 counts (bucket-major); bstart[b] = scan at (b, chunk 0)
__global__ void k_scan64k(const int* __restrict__ counts, int* __restrict__ bases,
                          int* __restrict__ bstart) {
    __shared__ int s[1024];
    int t = threadIdx.x;
    int base_i = t * 64;
    int sum = 0;
    for (int i = 0; i < 64; ++i) sum += counts[base_i + i];
    s[t] = sum;
    __syncthreads();
    for (int o = 1; o < 1024; o <<= 1) {
        int x = (t >= o) ? s[t - o] : 0;
        __syncthreads();
        s[t] += x;
        __syncthreads();
    }
    int run = t ? s[t - 1] : 0;
    for (int i = 0; i < 64; ++i) {
        int idx = base_i + i;
        int cv = counts[idx];
        bases[idx] = run;
        if ((idx & (NCHUNK - 1)) == 0) bstart[idx >> 8] = run;
        run += cv;
    }
    if (t == 0) bstart[NBUCK] = NEDGES;
}

// per-chunk LDS counting sort by bucket, then per-warp bucket-run coalesced write-out
__global__ __launch_bounds__(256) void k_bin_sorted(const int* __restrict__ src,
                                                    const int* __restrict__ dst,
                                                    const int* __restrict__ bases,
                                                    unsigned* __restrict__ packed) {
    __shared__ unsigned outp[CHUNK_E];   // 37.3 KB
    __shared__ int hist[NBUCK];          // doubles as cursor
    __shared__ int tmp[NBUCK];
    __shared__ int basel[NBUCK + 1];
    __shared__ int gbase[NBUCK];
    int t = threadIdx.x;
    int e0 = blockIdx.x * CHUNK_E;
    hist[t] = 0;
    gbase[t] = bases[t * NCHUNK + blockIdx.x];
    __syncthreads();
    // pass 1: bucket histogram (streaming NT read of dst)
    for (int i = t; i < CHUNK_E; i += 256) {
        int d = __builtin_nontemporal_load(&dst[e0 + i]);
        atomicAdd(&hist[d / BUCKET_N], 1);
    }
    __syncthreads();
    int hv = hist[t];
    tmp[t] = hv;
    __syncthreads();
    for (int o = 1; o < 256; o <<= 1) {
        int x = (t >= o) ? tmp[t - o] : 0;
        __syncthreads();
        tmp[t] += x;
        __syncthreads();
    }
    basel[t] = tmp[t] - hv;   // exclusive
    if (t == 255) basel[256] = tmp[255];
    hist[t] = tmp[t] - hv;    // cursor
    __syncthreads();
    // pass 2: scatter into LDS (re-read dst+src, NT)
    for (int i = t; i < CHUNK_E; i += 256) {
        int d = __builtin_nontemporal_load(&dst[e0 + i]);
        int sv = __builtin_nontemporal_load(&src[e0 + i]);
        int b = d / BUCKET_N;
        int pos = atomicAdd(&hist[b], 1);
        outp[pos] = ((unsigned)sv << FPACK_SHIFT) | (unsigned)(d - b * BUCKET_N);
    }
    __syncthreads();
    // write-out: warp w copies runs of buckets w, w+4, ... (contiguous LDS -> contiguous global)
    int warp = t >> 6, lane = t & 63;
    for (int b = warp; b < NBUCK; b += 4) {
        int s0 = basel[b], s1 = basel[b + 1], gb = gbase[b];
        for (int i = s0 + lane; i < s1; i += 64)
            packed[gb + (i - s0)] = outp[i];
    }
}

// one block per bucket: LDS degree hist -> scan -> scatter -> coalesced writes of deg/rowstart/dinv/csr
__global__ __launch_bounds__(256) void k_build(const unsigned* __restrict__ packed,
                                               const int* __restrict__ bstart,
                                               int* __restrict__ deg, int* __restrict__ rowstart,
                                               float* __restrict__ dinv, int* __restrict__ csr) {
    __shared__ unsigned pk[CAP];   // 40 KB
    __shared__ int csr_l[CAP];     // 40 KB
    __shared__ int ldeg[768];
    __shared__ int lrow[768];
    __shared__ int part[256];
    int t = threadIdx.x;
    int b = blockIdx.x;
    int lo = bstart[b], hi = bstart[b + 1];
    int len = hi - lo;
    if (len > CAP) len = CAP;
    for (int i = t; i < len; i += 256) pk[i] = packed[lo + i];
    for (int i = t; i < 768; i += 256) ldeg[i] = 0;
    __syncthreads();
    for (int i = t; i < len; i += 256) atomicAdd(&ldeg[pk[i] & FPACK_MASK], 1);
    __syncthreads();
    int a0 = ldeg[t * 3], a1 = ldeg[t * 3 + 1], a2 = ldeg[t * 3 + 2];
    part[t] = a0 + a1 + a2;
    __syncthreads();
    for (int o = 1; o < 256; o <<= 1) {
        int x = (t >= o) ? part[t - o] : 0;
        __syncthreads();
        part[t] += x;
        __syncthreads();
    }
    int run = t ? part[t - 1] : 0;
    lrow[t * 3] = run;
    lrow[t * 3 + 1] = run + a0;
    lrow[t * 3 + 2] = run + a0 + a1;
    __syncthreads();
    int n0 = b * BUCKET_N;
    int nnode = NNODES - n0; if (nnode > BUCKET_N) nnode = BUCKET_N;
    for (int l = t; l < nnode; l += 256) {
        int dg = ldeg[l];
        deg[n0 + l] = dg;
        rowstart[n0 + l] = lo + lrow[l];
        dinv[n0 + l] = rsqrtf((float)(dg + 1));
    }
    for (int l = t; l < 768; l += 256) ldeg[l] = lrow[l];   // cursor
    __syncthreads();
    for (int i = t; i < len; i += 256) {
        unsigned v = pk[i];
        int pos = atomicAdd(&ldeg[v & FPACK_MASK], 1);
        csr_l[pos] = (int)(v >> FPACK_SHIFT);
    }
    __syncthreads();
    for (int i = t; i < len; i += 256) csr[lo + i] = csr_l[i];
}

// ================= GCN layers =================

__global__ void k_pre1(const float* __restrict__ x, const float* __restrict__ dinv,
                       float* __restrict__ xs8) {
    unsigned t = blockIdx.x * blockDim.x + threadIdx.x;
    if (t >= (unsigned)NNODES * 8u) return;
    unsigned n = t >> 3, c = t & 7u;
    xs8[t] = (c < 5u) ? x[n * 5u + c] * dinv[n] : 0.f;
}

__global__ void k_gather8v(const int* __restrict__ rowstart, const int* __restrict__ deg,
                           const int* __restrict__ csr, const float4* __restrict__ xs,
                           float4* __restrict__ agg) {
    unsigned t = blockIdx.x * blockDim.x + threadIdx.x;
    unsigned g = t >> 1, c = t & 1u;
    if (g >= NNODES) return;
    int rs = rowstart[g], d = deg[g];
    float4 acc = xs[g * 2u + c];
    int j = 0;
    for (; j + 4 <= d; j += 4) {
        int s0 = csr[rs + j], s1 = csr[rs + j + 1], s2 = csr[rs + j + 2], s3 = csr[rs + j + 3];
        float4 v0 = xs[(unsigned)s0 * 2u + c], v1 = xs[(unsigned)s1 * 2u + c];
        float4 v2 = xs[(unsigned)s2 * 2u + c], v3 = xs[(unsigned)s3 * 2u + c];
        acc.x += v0.x + v1.x + v2.x + v3.x;
        acc.y += v0.y + v1.y + v2.y + v3.y;
        acc.z += v0.z + v1.z + v2.z + v3.z;
        acc.w += v0.w + v1.w + v2.w + v3.w;
    }
    for (; j < d; ++j) {
        float4 v = xs[(unsigned)csr[rs + j] * 2u + c];
        acc.x += v.x; acc.y += v.y; acc.z += v.z; acc.w += v.w;
    }
    agg[g * 2u + c] = acc;
}

__global__ void k_gather16v(const int* __restrict__ rowstart, const int* __restrict__ deg,
                            const int* __restrict__ csr, const float4* __restrict__ gs,
                            float4* __restrict__ agg) {
    unsigned t = blockIdx.x * blockDim.x + threadIdx.x;
    unsigned g = t >> 2, c = t & 3u;
    if (g >= NNODES) return;
    int rs = rowstart[g], d = deg[g];
    float4 acc = gs[g * 4u + c];
    int j = 0;
    for (; j + 4 <= d; j += 4) {
        int s0 = csr[rs + j], s1 = csr[rs + j + 1], s2 = csr[rs + j + 2], s3 = csr[rs + j + 3];
        float4 v0 = gs[(unsigned)s0 * 4u + c], v1 = gs[(unsigned)s1 * 4u + c];
        float4 v2 = gs[(unsigned)s2 * 4u + c], v3 = gs[(unsigned)s3 * 4u + c];
        acc.x += v0.x + v1.x + v2.x + v3.x;
        acc.y += v0.y + v1.y + v2.y + v3.y;
        acc.z += v0.z + v1.z + v2.z + v3.z;
        acc.w += v0.w + v1.w + v2.w + v3.w;
    }
    for (; j < d; ++j) {
        float4 v = gs[(unsigned)csr[rs + j] * 4u + c];
        acc.x += v.x; acc.y += v.y; acc.z += v.z; acc.w += v.w;
    }
    agg[g * 4u + c] = acc;
}

__global__ void k_gather4_final(const int* __restrict__ rowstart, const int* __restrict__ deg,
                                const int* __restrict__ csr, const float4* __restrict__ g3,
                                const float* __restrict__ dinv, const float* __restrict__ b3,
                                float* __restrict__ h3) {
    unsigned g = blockIdx.x * blockDim.x + threadIdx.x;
    if (g >= NNODES) return;
    int rs = rowstart[g], d = deg[g];
    float4 acc = g3[g];
    int j = 0;
    for (; j + 4 <= d; j += 4) {
        int s0 = csr[rs + j], s1 = csr[rs + j + 1], s2 = csr[rs + j + 2], s3 = csr[rs + j + 3];
        float4 v0 = g3[s0], v1 = g3[s1], v2 = g3[s2], v3 = g3[s3];
        acc.x += v0.x + v1.x + v2.x + v3.x;
        acc.y += v0.y + v1.y + v2.y + v3.y;
        acc.z += v0.z + v1.z + v2.z + v3.z;
    }
    for (; j < d; ++j) {
        float4 v = g3[csr[rs + j]];
        acc.x += v.x; acc.y += v.y; acc.z += v.z;
    }
    float di = dinv[g];
    float o0 = acc.x * di + b3[0];
    float o1 = acc.y * di + b3[1];
    float o2 = acc.z * di + b3[2];
    h3[g * 3u + 0] = o0 > 0.f ? o0 : 0.f;
    h3[g * 3u + 1] = o1 > 0.f ? o1 : 0.f;
    h3[g * 3u + 2] = o2 > 0.f ? o2 : 0.f;
}

__global__ void k_mm12(const float* __restrict__ agg8, const float* __restrict__ dinv,
                       const float* __restrict__ W1, const float* __restrict__ b1,
                       const float* __restrict__ W2, float* __restrict__ g2s) {
    __shared__ float W1s[5 * 32], W2s[32 * 16], b1s[32];
    int tid = threadIdx.x;  // 256
    if (tid < 5 * 32) W1s[tid] = W1[tid];
    if (tid < 32) b1s[tid] = b1[tid];
    for (int i = tid; i < 32 * 16; i += 256) W2s[i] = W2[i];
    __syncthreads();

    unsigned n = blockIdx.x * blockDim.x + tid;
    if (n >= NNODES) return;
    float di = dinv[n];
    float a[5];
#pragma unroll
    for (int k = 0; k < 5; ++k) a[k] = agg8[n * 8u + k] * di;

    float h[32];
#pragma unroll
    for (int j = 0; j < 32; ++j) {
        float acc = b1s[j];
#pragma unroll
        for (int k = 0; k < 5; ++k) acc += a[k] * W1s[k * 32 + j];
        h[j] = acc > 0.f ? acc : 0.f;
    }
    float g[16];
#pragma unroll
    for (int c = 0; c < 16; ++c) g[c] = 0.f;
#pragma unroll
    for (int j = 0; j < 32; ++j) {
        float hj = h[j];
#pragma unroll
        for (int c = 0; c < 16; ++c) g[c] += hj * W2s[j * 16 + c];
    }
#pragma unroll
    for (int c = 0; c < 16; ++c) g2s[n * 16u + c] = g[c] * di;
}

__global__ void k_mm3(const float* __restrict__ agg2, const float* __restrict__ dinv,
                      const float* __restrict__ b2, const float* __restrict__ W3,
                      float* __restrict__ g3s4) {
    __shared__ float W3s[16 * 3], b2s[16];
    int tid = threadIdx.x;
    if (tid < 16 * 3) W3s[tid] = W3[tid];
    if (tid < 16) b2s[tid] = b2[tid];
    __syncthreads();

    unsigned n = blockIdx.x * blockDim.x + tid;
    if (n >= NNODES) return;
    float di = dinv[n];
    float t2[16];
#pragma unroll
    for (int j = 0; j < 16; ++j) {
        float v = agg2[n * 16u + j] * di + b2s[j];
        t2[j] = v > 0.f ? v : 0.f;
    }
    float g[3] = {0.f, 0.f, 0.f};
#pragma unroll
    for (int j = 0; j < 16; ++j) {
        float tj = t2[j];
#pragma unroll
        for (int c = 0; c < 3; ++c) g[c] += tj * W3s[j * 3 + c];
    }
#pragma unroll
    for (int c = 0; c < 3; ++c) g3s4[n * 4u + c] = g[c] * di;
    g3s4[n * 4u + 3] = 0.f;
}

// ================= head =================

__global__ void k_head2(const float* __restrict__ h3, const float* __restrict__ Wl1,
                        float* __restrict__ zpart) {
    __shared__ float hrow[SEGK];
    __shared__ float part[8][32];
    int b = blockIdx.x >> 5, seg = blockIdx.x & 31;
    int k0 = seg * SEGK;
    int kend = k0 + SEGK; if (kend > HEADK) kend = HEADK;
    int cnt = kend - k0;
    for (int k = threadIdx.x; k < cnt; k += 256) hrow[k] = h3[b * HEADK + k0 + k];
    __syncthreads();
    int j = threadIdx.x & 31, g = threadIdx.x >> 5;
    float acc = 0.f;
    for (int k = g; k < cnt; k += 8) acc += hrow[k] * Wl1[(k0 + k) * 32 + j];
    part[g][j] = acc;
    __syncthreads();
    if (threadIdx.x < 32) {
        float s = 0.f;
#pragma unroll
        for (int g2 = 0; g2 < 8; ++g2) s += part[g2][j];
        zpart[(seg * NB + b) * 32 + j] = s;
    }
}

__global__ void k_bn_final(const float* __restrict__ zpart, const float* __restrict__ bl1,
                           const float* __restrict__ gamma, const float* __restrict__ beta,
                           const float* __restrict__ Wl2, const float* __restrict__ bl2,
                           float* __restrict__ out) {
    __shared__ float zs[NB][32];
    __shared__ float scale[32], shift[32];
    int tid = threadIdx.x;  // 256
    for (int i = tid; i < NB * 32; i += 256) {
        float v = bl1[i & 31];
#pragma unroll
        for (int sgm = 0; sgm < HEAD_SEG; ++sgm) v += zpart[sgm * NB * 32 + i];
        zs[i >> 5][i & 31] = v;
    }
    __syncthreads();
    if (tid < 32) {
        float m = 0.f, v = 0.f;
        for (int b = 0; b < NB; ++b) { float xv = zs[b][tid]; m += xv; v += xv * xv; }
        m /= (float)NB;
        v = v / (float)NB - m * m;
        float sc = gamma[tid] * rsqrtf(v + BN_EPS);
        scale[tid] = sc;
        shift[tid] = beta[tid] - m * sc;
    }
    __syncthreads();
    if (tid < NB) {
        float acc = bl2[0];
#pragma unroll
        for (int j = 0; j < 32; ++j) {
            float zv = zs[tid][j] * scale[j] + shift[j];
            zv = zv > 0.f ? zv : 0.f;
            acc += zv * Wl2[j];
        }
        out[tid] = acc;
    }
}

// ================= launch =================

extern "C" void kernel_launch(void* const* d_in, const int* in_sizes, int n_in,
                              void* d_out, int out_size, void* d_ws, size_t ws_size,
                              hipStream_t stream) {
    const float* x    = (const float*)d_in[0];
    const int*   ei   = (const int*)d_in[1];
    const float* W1   = (const float*)d_in[2];
    const float* b1   = (const float*)d_in[3];
    const float* W2   = (const float*)d_in[4];
    const float* b2   = (const float*)d_in[5];
    const float* W3   = (const float*)d_in[6];
    const float* b3   = (const float*)d_in[7];
    const float* Wl1  = (const float*)d_in[8];
    const float* bl1  = (const float*)d_in[9];
    const float* gamma= (const float*)d_in[10];
    const float* beta = (const float*)d_in[11];
    const float* Wl2  = (const float*)d_in[12];
    const float* bl2  = (const float*)d_in[13];

    const int* src = ei;            // edge_index[0]
    const int* dst = ei + NEDGES;   // edge_index[1]

    char* ws = (char*)d_ws;
    size_t off = 0;
    float*    dinv     = (float*)   (ws + off); off += (size_t)NNODES * 4;
    int*      deg      = (int*)     (ws + off); off += (size_t)NNODES * 4;
    int*      counts   = (int*)     (ws + off); off += (size_t)NBUCK * NCHUNK * 4;
    int*      bases    = (int*)     (ws + off); off += (size_t)NBUCK * NCHUNK * 4;
    int*      bstart   = (int*)     (ws + off); off += (size_t)(NBUCK + 1) * 4;
    off = (off + 255) & ~(size_t)255;
    unsigned* packed   = (unsigned*)(ws + off); off += (size_t)NEDGES * 4;
    int*      rowstart = (int*)     (ws + off); off += (size_t)NNODES * 4;
    int*      csr      = (int*)     (ws + off); off += (size_t)NEDGES * 4;
    float*    xs8      = (float*)   (ws + off); off += (size_t)NNODES * 8 * 4;
    float*    agg8     = (float*)   (ws + off); off += (size_t)NNODES * 8 * 4;
    float*    g2s      = (float*)   (ws + off); off += (size_t)NNODES * 16 * 4;
    float*    agg2     = (float*)   (ws + off); off += (size_t)NNODES * 16 * 4;
    float*    g3s4     = (float*)   (ws + off); off += (size_t)NNODES * 4 * 4;
    float*    h3       = (float*)   (ws + off); off += (size_t)NNODES * 3 * 4;
    float*    zpart    = (float*)   (ws + off); off += (size_t)HEAD_SEG * NB * 32 * 4;

    float* outp = (float*)d_out;

    // ---- CSR build: all scattered stores staged through LDS, all global stores coalesced
    k_count<<<NCHUNK, 256, 0, stream>>>(dst, counts);
    k_scan64k<<<1, 1024, 0, stream>>>(counts, bases, bstart);
    k_bin_sorted<<<NCHUNK, 256, 0, stream>>>(src, dst, bases, packed);
    k_build<<<NBUCK, 256, 0, stream>>>(packed, bstart, deg, rowstart, dinv, csr);

    // ---- layer 1: aggregate in 5-dim (padded 8) input space, gather-based
    k_pre1<<<(int)(((unsigned)NNODES * 8u + 255) / 256), 256, 0, stream>>>(x, dinv, xs8);
    k_gather8v<<<(int)(((unsigned)NNODES * 2u + 255) / 256), 256, 0, stream>>>(
        rowstart, deg, csr, (const float4*)xs8, (float4*)agg8);

    // ---- fused mm1 + relu + mm2 + prescale
    k_mm12<<<(NNODES + 255) / 256, 256, 0, stream>>>(agg8, dinv, W1, b1, W2, g2s);
    k_gather16v<<<(int)(((unsigned)NNODES * 4u + 255) / 256), 256, 0, stream>>>(
        rowstart, deg, csr, (const float4*)g2s, (float4*)agg2);

    // ---- fused relu(layer2) + mm3 + prescale
    k_mm3<<<(NNODES + 255) / 256, 256, 0, stream>>>(agg2, dinv, b2, W3, g3s4);
    k_gather4_final<<<(NNODES + 255) / 256, 256, 0, stream>>>(
        rowstart, deg, csr, (const float4*)g3s4, dinv, b3, h3);

    // ---- head + BN + final linear
    k_head2<<<NB * HEAD_SEG, 256, 0, stream>>>(h3, Wl1, zpart);
    k_bn_final<<<1, 256, 0, stream>>>(zpart, bl1, gamma, beta, Wl2, bl2, outp);
}

// Round 8
// 169.326 us; speedup vs baseline: 2.3311x; 1.4473x over previous
//
#include <hip/hip_runtime.h>

#define NNODES 149120
#define NEDGES 2385920
#define NB 64
#define NPMTS 2330
#define HEADK (NPMTS * 3)   // 6990
#define BN_EPS 1e-5f

#define NBUCK 256
#define BUCKET_N 583                    // 256*583 = 149248 >= NNODES
#define NCHUNK 1024
#define CHUNK_E (NEDGES / NCHUNK)       // 2330 (exact)
#define FPACK_SHIFT 10
#define FPACK_MASK 1023u
#define CAP 10240                       // max edges per bucket (mean 9329, sigma ~97)

#define HEAD_SEG 32
#define SEGK ((HEADK + HEAD_SEG - 1) / HEAD_SEG)   // 219

// ================= CSR build: count -> 2-level scan -> LDS-sorted bin -> per-bucket build =================

// per-(bucket,chunk) histogram, bucket-major: counts[b*NCHUNK + chunk]
__global__ void k_count(const int* __restrict__ dst, int* __restrict__ counts) {
    __shared__ int c[NBUCK];
    c[threadIdx.x] = 0;
    __syncthreads();
    int e0 = blockIdx.x * CHUNK_E;
    for (int e = e0 + threadIdx.x; e < e0 + CHUNK_E; e += 256) {
        int d = __builtin_nontemporal_load(&dst[e]);
        atomicAdd(&c[d / BUCKET_N], 1);
    }
    __syncthreads();
    counts[threadIdx.x * NCHUNK + blockIdx.x] = c[threadIdx.x];
}

// level A: per-bucket exclusive scan over its 1024 chunk counts (coalesced int4), emit bucket total
__global__ void k_scanA(const int* __restrict__ counts, int* __restrict__ bases,
                        int* __restrict__ btot) {
    __shared__ int s[256];
    int b = blockIdx.x, t = threadIdx.x;
    const int4* row = (const int4*)(counts + b * NCHUNK);
    int4 v = row[t];
    int sum = v.x + v.y + v.z + v.w;
    s[t] = sum;
    __syncthreads();
    for (int o = 1; o < 256; o <<= 1) {
        int x = (t >= o) ? s[t - o] : 0;
        __syncthreads();
        s[t] += x;
        __syncthreads();
    }
    int run = t ? s[t - 1] : 0;
    int4 o;
    o.x = run;
    o.y = run + v.x;
    o.z = run + v.x + v.y;
    o.w = run + v.x + v.y + v.z;
    ((int4*)(bases + b * NCHUNK))[t] = o;
    if (t == 255) btot[b] = s[255];
}

// level B: exclusive scan of 256 bucket totals -> bstart[257]
__global__ void k_scanB(const int* __restrict__ btot, int* __restrict__ bstart) {
    __shared__ int s[256];
    int t = threadIdx.x;
    int v = btot[t];
    s[t] = v;
    __syncthreads();
    for (int o = 1; o < 256; o <<= 1) {
        int x = (t >= o) ? s[t - o] : 0;
        __syncthreads();
        s[t] += x;
        __syncthreads();
    }
    bstart[t] = s[t] - v;
    if (t == 255) bstart[256] = s[255];
}

// per-chunk LDS counting sort by bucket, then 8-lane-group bucket-run coalesced write-out
__global__ __launch_bounds__(256) void k_bin_sorted(const int* __restrict__ src,
                                                    const int* __restrict__ dst,
                                                    const int* __restrict__ bases,
                                                    const int* __restrict__ bstart,
                                                    unsigned* __restrict__ packed) {
    __shared__ unsigned ds[CHUNK_E];     // 9.3 KB
    __shared__ unsigned outp[CHUNK_E];   // 9.3 KB
    __shared__ int hist[NBUCK];          // doubles as cursor
    __shared__ int tmp[NBUCK];
    __shared__ int basel[NBUCK + 1];
    __shared__ int gbase[NBUCK];
    int t = threadIdx.x;
    int e0 = blockIdx.x * CHUNK_E;
    hist[t] = 0;
    gbase[t] = bstart[t] + bases[t * NCHUNK + blockIdx.x];
    __syncthreads();
    // pass 1: stage dst in LDS + bucket histogram
    for (int i = t; i < CHUNK_E; i += 256) {
        int d = __builtin_nontemporal_load(&dst[e0 + i]);
        ds[i] = (unsigned)d;
        atomicAdd(&hist[d / BUCKET_N], 1);
    }
    __syncthreads();
    int hv = hist[t];
    tmp[t] = hv;
    __syncthreads();
    for (int o = 1; o < 256; o <<= 1) {
        int x = (t >= o) ? tmp[t - o] : 0;
        __syncthreads();
        tmp[t] += x;
        __syncthreads();
    }
    basel[t] = tmp[t] - hv;   // exclusive
    if (t == 255) basel[256] = tmp[255];
    hist[t] = tmp[t] - hv;    // cursor
    __syncthreads();
    // pass 2: scatter into LDS (dst from LDS, src streamed NT)
    for (int i = t; i < CHUNK_E; i += 256) {
        unsigned d = ds[i];
        int sv = __builtin_nontemporal_load(&src[e0 + i]);
        unsigned b = d / BUCKET_N;
        int pos = atomicAdd(&hist[b], 1);
        outp[pos] = ((unsigned)sv << FPACK_SHIFT) | (d - b * BUCKET_N);
    }
    __syncthreads();
    // write-out: 32 groups of 8 lanes; group handles buckets gid, gid+32, ... (runs ~9 words)
    int gid = t >> 3, glane = t & 7;
    for (int b = gid; b < NBUCK; b += 32) {
        int s0 = basel[b], s1 = basel[b + 1], gb = gbase[b];
        for (int i = s0 + glane; i < s1; i += 8)
            packed[gb + (i - s0)] = outp[i];
    }
}

// one block per bucket: LDS degree hist -> scan -> scatter -> coalesced writes of deg/rowstart/dinv/csr
__global__ __launch_bounds__(256) void k_build(const unsigned* __restrict__ packed,
                                               const int* __restrict__ bstart,
                                               int* __restrict__ deg, int* __restrict__ rowstart,
                                               float* __restrict__ dinv, int* __restrict__ csr) {
    __shared__ unsigned pk[CAP];   // 40 KB
    __shared__ int csr_l[CAP];     // 40 KB
    __shared__ int ldeg[768];
    __shared__ int lrow[768];
    __shared__ int part[256];
    int t = threadIdx.x;
    int b = blockIdx.x;
    int lo = bstart[b], hi = bstart[b + 1];
    int len = hi - lo;
    if (len > CAP) len = CAP;
    for (int i = t; i < len; i += 256) pk[i] = packed[lo + i];
    for (int i = t; i < 768; i += 256) ldeg[i] = 0;
    __syncthreads();
    for (int i = t; i < len; i += 256) atomicAdd(&ldeg[pk[i] & FPACK_MASK], 1);
    __syncthreads();
    int a0 = ldeg[t * 3], a1 = ldeg[t * 3 + 1], a2 = ldeg[t * 3 + 2];
    part[t] = a0 + a1 + a2;
    __syncthreads();
    for (int o = 1; o < 256; o <<= 1) {
        int x = (t >= o) ? part[t - o] : 0;
        __syncthreads();
        part[t] += x;
        __syncthreads();
    }
    int run = t ? part[t - 1] : 0;
    lrow[t * 3] = run;
    lrow[t * 3 + 1] = run + a0;
    lrow[t * 3 + 2] = run + a0 + a1;
    __syncthreads();
    int n0 = b * BUCKET_N;
    int nnode = NNODES - n0; if (nnode > BUCKET_N) nnode = BUCKET_N;
    for (int l = t; l < nnode; l += 256) {
        int dg = ldeg[l];
        deg[n0 + l] = dg;
        rowstart[n0 + l] = lo + lrow[l];
        dinv[n0 + l] = rsqrtf((float)(dg + 1));
    }
    for (int l = t; l < 768; l += 256) ldeg[l] = lrow[l];   // cursor
    __syncthreads();
    for (int i = t; i < len; i += 256) {
        unsigned v = pk[i];
        int pos = atomicAdd(&ldeg[v & FPACK_MASK], 1);
        csr_l[pos] = (int)(v >> FPACK_SHIFT);
    }
    __syncthreads();
    for (int i = t; i < len; i += 256) csr[lo + i] = csr_l[i];
}

// ================= GCN layers =================

__global__ void k_pre1(const float* __restrict__ x, const float* __restrict__ dinv,
                       float* __restrict__ xs8) {
    unsigned t = blockIdx.x * blockDim.x + threadIdx.x;
    if (t >= (unsigned)NNODES * 8u) return;
    unsigned n = t >> 3, c = t & 7u;
    xs8[t] = (c < 5u) ? x[n * 5u + c] * dinv[n] : 0.f;
}

__global__ void k_gather8v(const int* __restrict__ rowstart, const int* __restrict__ deg,
                           const int* __restrict__ csr, const float4* __restrict__ xs,
                           float4* __restrict__ agg) {
    unsigned t = blockIdx.x * blockDim.x + threadIdx.x;
    unsigned g = t >> 1, c = t & 1u;
    if (g >= NNODES) return;
    int rs = rowstart[g], d = deg[g];
    float4 acc = xs[g * 2u + c];
    int j = 0;
    for (; j + 4 <= d; j += 4) {
        int s0 = csr[rs + j], s1 = csr[rs + j + 1], s2 = csr[rs + j + 2], s3 = csr[rs + j + 3];
        float4 v0 = xs[(unsigned)s0 * 2u + c], v1 = xs[(unsigned)s1 * 2u + c];
        float4 v2 = xs[(unsigned)s2 * 2u + c], v3 = xs[(unsigned)s3 * 2u + c];
        acc.x += v0.x + v1.x + v2.x + v3.x;
        acc.y += v0.y + v1.y + v2.y + v3.y;
        acc.z += v0.z + v1.z + v2.z + v3.z;
        acc.w += v0.w + v1.w + v2.w + v3.w;
    }
    for (; j < d; ++j) {
        float4 v = xs[(unsigned)csr[rs + j] * 2u + c];
        acc.x += v.x; acc.y += v.y; acc.z += v.z; acc.w += v.w;
    }
    agg[g * 2u + c] = acc;
}

// fused: gather agg2 + t2 = relu(agg2*dinv + b2) + g3 = (t2@W3)*dinv  (shfl-reduce over 4-lane group)
__global__ void k_gather16_mm3(const int* __restrict__ rowstart, const int* __restrict__ deg,
                               const int* __restrict__ csr, const float4* __restrict__ gs,
                               const float* __restrict__ dinv, const float* __restrict__ b2,
                               const float* __restrict__ W3, float4* __restrict__ g3s4) {
    __shared__ float W3s[16 * 3], b2s[16];
    int tid = threadIdx.x;
    if (tid < 16 * 3) W3s[tid] = W3[tid];
    if (tid < 16) b2s[tid] = b2[tid];
    __syncthreads();
    unsigned t = blockIdx.x * blockDim.x + tid;
    unsigned g = t >> 2, c = t & 3u;
    if (g >= NNODES) return;
    int rs = rowstart[g], d = deg[g];
    float4 acc = gs[g * 4u + c];
    int j = 0;
    for (; j + 4 <= d; j += 4) {
        int s0 = csr[rs + j], s1 = csr[rs + j + 1], s2 = csr[rs + j + 2], s3 = csr[rs + j + 3];
        float4 v0 = gs[(unsigned)s0 * 4u + c], v1 = gs[(unsigned)s1 * 4u + c];
        float4 v2 = gs[(unsigned)s2 * 4u + c], v3 = gs[(unsigned)s3 * 4u + c];
        acc.x += v0.x + v1.x + v2.x + v3.x;
        acc.y += v0.y + v1.y + v2.y + v3.y;
        acc.z += v0.z + v1.z + v2.z + v3.z;
        acc.w += v0.w + v1.w + v2.w + v3.w;
    }
    for (; j < d; ++j) {
        float4 v = gs[(unsigned)csr[rs + j] * 4u + c];
        acc.x += v.x; acc.y += v.y; acc.z += v.z; acc.w += v.w;
    }
    float di = dinv[g];
    float a[4] = {acc.x, acc.y, acc.z, acc.w};
    float p0 = 0.f, p1 = 0.f, p2 = 0.f;
#pragma unroll
    for (int jj = 0; jj < 4; ++jj) {
        float v = a[jj] * di + b2s[c * 4 + jj];
        v = v > 0.f ? v : 0.f;
        p0 += v * W3s[(c * 4 + jj) * 3 + 0];
        p1 += v * W3s[(c * 4 + jj) * 3 + 1];
        p2 += v * W3s[(c * 4 + jj) * 3 + 2];
    }
    p0 += __shfl_xor(p0, 1); p0 += __shfl_xor(p0, 2);
    p1 += __shfl_xor(p1, 1); p1 += __shfl_xor(p1, 2);
    p2 += __shfl_xor(p2, 1); p2 += __shfl_xor(p2, 2);
    if (c == 0) {
        float4 o; o.x = p0 * di; o.y = p1 * di; o.z = p2 * di; o.w = 0.f;
        g3s4[g] = o;
    }
}

__global__ void k_gather4_final(const int* __restrict__ rowstart, const int* __restrict__ deg,
                                const int* __restrict__ csr, const float4* __restrict__ g3,
                                const float* __restrict__ dinv, const float* __restrict__ b3,
                                float* __restrict__ h3) {
    unsigned g = blockIdx.x * blockDim.x + threadIdx.x;
    if (g >= NNODES) return;
    int rs = rowstart[g], d = deg[g];
    float4 acc = g3[g];
    int j = 0;
    for (; j + 4 <= d; j += 4) {
        int s0 = csr[rs + j], s1 = csr[rs + j + 1], s2 = csr[rs + j + 2], s3 = csr[rs + j + 3];
        float4 v0 = g3[s0], v1 = g3[s1], v2 = g3[s2], v3 = g3[s3];
        acc.x += v0.x + v1.x + v2.x + v3.x;
        acc.y += v0.y + v1.y + v2.y + v3.y;
        acc.z += v0.z + v1.z + v2.z + v3.z;
    }
    for (; j < d; ++j) {
        float4 v = g3[csr[rs + j]];
        acc.x += v.x; acc.y += v.y; acc.z += v.z;
    }
    float di = dinv[g];
    float o0 = acc.x * di + b3[0];
    float o1 = acc.y * di + b3[1];
    float o2 = acc.z * di + b3[2];
    h3[g * 3u + 0] = o0 > 0.f ? o0 : 0.f;
    h3[g * 3u + 1] = o1 > 0.f ? o1 : 0.f;
    h3[g * 3u + 2] = o2 > 0.f ? o2 : 0.f;
}

__global__ void k_mm12(const float* __restrict__ agg8, const float* __restrict__ dinv,
                       const float* __restrict__ W1, const float* __restrict__ b1,
                       const float* __restrict__ W2, float* __restrict__ g2s) {
    __shared__ float W1s[5 * 32], W2s[32 * 16], b1s[32];
    int tid = threadIdx.x;  // 256
    if (tid < 5 * 32) W1s[tid] = W1[tid];
    if (tid < 32) b1s[tid] = b1[tid];
    for (int i = tid; i < 32 * 16; i += 256) W2s[i] = W2[i];
    __syncthreads();

    unsigned n = blockIdx.x * blockDim.x + tid;
    if (n >= NNODES) return;
    float di = dinv[n];
    float a[5];
#pragma unroll
    for (int k = 0; k < 5; ++k) a[k] = agg8[n * 8u + k] * di;

    float h[32];
#pragma unroll
    for (int j = 0; j < 32; ++j) {
        float acc = b1s[j];
#pragma unroll
        for (int k = 0; k < 5; ++k) acc += a[k] * W1s[k * 32 + j];
        h[j] = acc > 0.f ? acc : 0.f;
    }
    float g[16];
#pragma unroll
    for (int c = 0; c < 16; ++c) g[c] = 0.f;
#pragma unroll
    for (int j = 0; j < 32; ++j) {
        float hj = h[j];
#pragma unroll
        for (int c = 0; c < 16; ++c) g[c] += hj * W2s[j * 16 + c];
    }
#pragma unroll
    for (int c = 0; c < 16; ++c) g2s[n * 16u + c] = g[c] * di;
}

// ================= head =================

__global__ void k_head2(const float* __restrict__ h3, const float* __restrict__ Wl1,
                        float* __restrict__ zpart) {
    __shared__ float hrow[SEGK];
    __shared__ float part[8][32];
    int b = blockIdx.x >> 5, seg = blockIdx.x & 31;
    int k0 = seg * SEGK;
    int kend = k0 + SEGK; if (kend > HEADK) kend = HEADK;
    int cnt = kend - k0;
    for (int k = threadIdx.x; k < cnt; k += 256) hrow[k] = h3[b * HEADK + k0 + k];
    __syncthreads();
    int j = threadIdx.x & 31, g = threadIdx.x >> 5;
    float acc = 0.f;
    for (int k = g; k < cnt; k += 8) acc += hrow[k] * Wl1[(k0 + k) * 32 + j];
    part[g][j] = acc;
    __syncthreads();
    if (threadIdx.x < 32) {
        float s = 0.f;
#pragma unroll
        for (int g2 = 0; g2 < 8; ++g2) s += part[g2][j];
        zpart[(seg * NB + b) * 32 + j] = s;
    }
}

__global__ void k_bn_final(const float* __restrict__ zpart, const float* __restrict__ bl1,
                           const float* __restrict__ gamma, const float* __restrict__ beta,
                           const float* __restrict__ Wl2, const float* __restrict__ bl2,
                           float* __restrict__ out) {
    __shared__ float zs[NB][32];
    __shared__ float scale[32], shift[32];
    int tid = threadIdx.x;  // 256
    for (int i = tid; i < NB * 32; i += 256) {
        float v = bl1[i & 31];
#pragma unroll
        for (int sgm = 0; sgm < HEAD_SEG; ++sgm) v += zpart[sgm * NB * 32 + i];
        zs[i >> 5][i & 31] = v;
    }
    __syncthreads();
    if (tid < 32) {
        float m = 0.f, v = 0.f;
        for (int b = 0; b < NB; ++b) { float xv = zs[b][tid]; m += xv; v += xv * xv; }
        m /= (float)NB;
        v = v / (float)NB - m * m;
        float sc = gamma[tid] * rsqrtf(v + BN_EPS);
        scale[tid] = sc;
        shift[tid] = beta[tid] - m * sc;
    }
    __syncthreads();
    if (tid < NB) {
        float acc = bl2[0];
#pragma unroll
        for (int j = 0; j < 32; ++j) {
            float zv = zs[tid][j] * scale[j] + shift[j];
            zv = zv > 0.f ? zv : 0.f;
            acc += zv * Wl2[j];
        }
        out[tid] = acc;
    }
}

// ================= launch =================

extern "C" void kernel_launch(void* const* d_in, const int* in_sizes, int n_in,
                              void* d_out, int out_size, void* d_ws, size_t ws_size,
                              hipStream_t stream) {
    const float* x    = (const float*)d_in[0];
    const int*   ei   = (const int*)d_in[1];
    const float* W1   = (const float*)d_in[2];
    const float* b1   = (const float*)d_in[3];
    const float* W2   = (const float*)d_in[4];
    const float* b2   = (const float*)d_in[5];
    const float* W3   = (const float*)d_in[6];
    const float* b3   = (const float*)d_in[7];
    const float* Wl1  = (const float*)d_in[8];
    const float* bl1  = (const float*)d_in[9];
    const float* gamma= (const float*)d_in[10];
    const float* beta = (const float*)d_in[11];
    const float* Wl2  = (const float*)d_in[12];
    const float* bl2  = (const float*)d_in[13];

    const int* src = ei;            // edge_index[0]
    const int* dst = ei + NEDGES;   // edge_index[1]

    char* ws = (char*)d_ws;
    size_t off = 0;
    float*    dinv     = (float*)   (ws + off); off += (size_t)NNODES * 4;
    int*      deg      = (int*)     (ws + off); off += (size_t)NNODES * 4;
    int*      counts   = (int*)     (ws + off); off += (size_t)NBUCK * NCHUNK * 4;
    int*      bases    = (int*)     (ws + off); off += (size_t)NBUCK * NCHUNK * 4;
    int*      btot     = (int*)     (ws + off); off += (size_t)NBUCK * 4;
    int*      bstart   = (int*)     (ws + off); off += (size_t)(NBUCK + 1) * 4;
    off = (off + 255) & ~(size_t)255;
    unsigned* packed   = (unsigned*)(ws + off); off += (size_t)NEDGES * 4;
    int*      rowstart = (int*)     (ws + off); off += (size_t)NNODES * 4;
    int*      csr      = (int*)     (ws + off); off += (size_t)NEDGES * 4;
    float*    xs8      = (float*)   (ws + off); off += (size_t)NNODES * 8 * 4;
    float*    agg8     = (float*)   (ws + off); off += (size_t)NNODES * 8 * 4;
    float*    g2s      = (float*)   (ws + off); off += (size_t)NNODES * 16 * 4;
    float*    g3s4     = (float*)   (ws + off); off += (size_t)NNODES * 4 * 4;
    float*    h3       = (float*)   (ws + off); off += (size_t)NNODES * 3 * 4;
    float*    zpart    = (float*)   (ws + off); off += (size_t)HEAD_SEG * NB * 32 * 4;

    float* outp = (float*)d_out;

    // ---- CSR build: count -> two-level scan -> LDS sort -> per-bucket build (all stores coalesced)
    k_count<<<NCHUNK, 256, 0, stream>>>(dst, counts);
    k_scanA<<<NBUCK, 256, 0, stream>>>(counts, bases, btot);
    k_scanB<<<1, 256, 0, stream>>>(btot, bstart);
    k_bin_sorted<<<NCHUNK, 256, 0, stream>>>(src, dst, bases, bstart, packed);
    k_build<<<NBUCK, 256, 0, stream>>>(packed, bstart, deg, rowstart, dinv, csr);

    // ---- layer 1: aggregate in 5-dim (padded 8) input space, gather-based
    k_pre1<<<(int)(((unsigned)NNODES * 8u + 255) / 256), 256, 0, stream>>>(x, dinv, xs8);
    k_gather8v<<<(int)(((unsigned)NNODES * 2u + 255) / 256), 256, 0, stream>>>(
        rowstart, deg, csr, (const float4*)xs8, (float4*)agg8);

    // ---- fused mm1 + relu + mm2 + prescale
    k_mm12<<<(NNODES + 255) / 256, 256, 0, stream>>>(agg8, dinv, W1, b1, W2, g2s);

    // ---- fused gather(layer2) + relu + mm3 + prescale
    k_gather16_mm3<<<(int)(((unsigned)NNODES * 4u + 255) / 256), 256, 0, stream>>>(
        rowstart, deg, csr, (const float4*)g2s, dinv, b2, W3, (float4*)g3s4);

    // ---- gather(layer3) + bias + relu
    k_gather4_final<<<(NNODES + 255) / 256, 256, 0, stream>>>(
        rowstart, deg, csr, (const float4*)g3s4, dinv, b3, h3);

    // ---- head + BN + final linear
    k_head2<<<NB * HEAD_SEG, 256, 0, stream>>>(h3, Wl1, zpart);
    k_bn_final<<<1, 256, 0, stream>>>(zpart, bl1, gamma, beta, Wl2, bl2, outp);
}

// Round 9
// 151.141 us; speedup vs baseline: 2.6115x; 1.1203x over previous
//
#include <hip/hip_runtime.h>

#define NNODES 149120
#define NEDGES 2385920
#define NB 64
#define NPMTS 2330
#define HEADK (NPMTS * 3)   // 6990
#define BN_EPS 1e-5f

#define NBUCK 256
#define BUCKET_N 583                    // 256*583 = 149248 >= NNODES
#define NCHUNK 1024
#define CHUNK_E (NEDGES / NCHUNK)       // 2330 (exact)
#define FPACK_SHIFT 10
#define FPACK_MASK 1023u
#define CAP 10240                       // max edges per bucket (mean 9329, sigma ~97)

#define HEAD_SEG 32
#define SEGK ((HEADK + HEAD_SEG - 1) / HEAD_SEG)   // 219
#define BGRP 16                         // batch groups
#define BPB (NB / BGRP)                 // 4 batches per block

typedef _Float16 h16;
struct alignas(16) h8 { h16 v[8]; };
struct alignas(8)  h4 { h16 v[4]; };

// ================= CSR build: count -> 2-level scan -> LDS-sorted bin -> per-bucket build =================

__global__ void k_count(const int* __restrict__ dst, int* __restrict__ counts) {
    __shared__ int c[NBUCK];
    c[threadIdx.x] = 0;
    __syncthreads();
    int e0 = blockIdx.x * CHUNK_E;
    for (int e = e0 + threadIdx.x; e < e0 + CHUNK_E; e += 256) {
        int d = __builtin_nontemporal_load(&dst[e]);
        atomicAdd(&c[d / BUCKET_N], 1);
    }
    __syncthreads();
    counts[threadIdx.x * NCHUNK + blockIdx.x] = c[threadIdx.x];
}

__global__ void k_scanA(const int* __restrict__ counts, int* __restrict__ bases,
                        int* __restrict__ btot) {
    __shared__ int s[256];
    int b = blockIdx.x, t = threadIdx.x;
    const int4* row = (const int4*)(counts + b * NCHUNK);
    int4 v = row[t];
    int sum = v.x + v.y + v.z + v.w;
    s[t] = sum;
    __syncthreads();
    for (int o = 1; o < 256; o <<= 1) {
        int x = (t >= o) ? s[t - o] : 0;
        __syncthreads();
        s[t] += x;
        __syncthreads();
    }
    int run = t ? s[t - 1] : 0;
    int4 o;
    o.x = run;
    o.y = run + v.x;
    o.z = run + v.x + v.y;
    o.w = run + v.x + v.y + v.z;
    ((int4*)(bases + b * NCHUNK))[t] = o;
    if (t == 255) btot[b] = s[255];
}

__global__ void k_scanB(const int* __restrict__ btot, int* __restrict__ bstart) {
    __shared__ int s[256];
    int t = threadIdx.x;
    int v = btot[t];
    s[t] = v;
    __syncthreads();
    for (int o = 1; o < 256; o <<= 1) {
        int x = (t >= o) ? s[t - o] : 0;
        __syncthreads();
        s[t] += x;
        __syncthreads();
    }
    bstart[t] = s[t] - v;
    if (t == 255) bstart[256] = s[255];
}

__global__ __launch_bounds__(256) void k_bin_sorted(const int* __restrict__ src,
                                                    const int* __restrict__ dst,
                                                    const int* __restrict__ bases,
                                                    const int* __restrict__ bstart,
                                                    unsigned* __restrict__ packed) {
    __shared__ unsigned ds[CHUNK_E];     // 9.3 KB
    __shared__ unsigned outp[CHUNK_E];   // 9.3 KB
    __shared__ int hist[NBUCK];
    __shared__ int tmp[NBUCK];
    __shared__ int basel[NBUCK + 1];
    __shared__ int gbase[NBUCK];
    int t = threadIdx.x;
    int e0 = blockIdx.x * CHUNK_E;
    hist[t] = 0;
    gbase[t] = bstart[t] + bases[t * NCHUNK + blockIdx.x];
    __syncthreads();
    for (int i = t; i < CHUNK_E; i += 256) {
        int d = __builtin_nontemporal_load(&dst[e0 + i]);
        ds[i] = (unsigned)d;
        atomicAdd(&hist[d / BUCKET_N], 1);
    }
    __syncthreads();
    int hv = hist[t];
    tmp[t] = hv;
    __syncthreads();
    for (int o = 1; o < 256; o <<= 1) {
        int x = (t >= o) ? tmp[t - o] : 0;
        __syncthreads();
        tmp[t] += x;
        __syncthreads();
    }
    basel[t] = tmp[t] - hv;
    if (t == 255) basel[256] = tmp[255];
    hist[t] = tmp[t] - hv;
    __syncthreads();
    for (int i = t; i < CHUNK_E; i += 256) {
        unsigned d = ds[i];
        int sv = __builtin_nontemporal_load(&src[e0 + i]);
        unsigned b = d / BUCKET_N;
        int pos = atomicAdd(&hist[b], 1);
        outp[pos] = ((unsigned)sv << FPACK_SHIFT) | (d - b * BUCKET_N);
    }
    __syncthreads();
    int gid = t >> 3, glane = t & 7;
    for (int b = gid; b < NBUCK; b += 32) {
        int s0 = basel[b], s1 = basel[b + 1], gb = gbase[b];
        for (int i = s0 + glane; i < s1; i += 8)
            packed[gb + (i - s0)] = outp[i];
    }
}

// one block per bucket: deg hist -> scan -> csr scatter (LDS) + coalesced writes; also xs8h = x*dinv (fp16)
__global__ __launch_bounds__(256) void k_build(const unsigned* __restrict__ packed,
                                               const int* __restrict__ bstart,
                                               const float* __restrict__ x,
                                               int* __restrict__ deg, int* __restrict__ rowstart,
                                               float* __restrict__ dinv, int* __restrict__ csr,
                                               h8* __restrict__ xs8h) {
    __shared__ unsigned pk[CAP];   // 40 KB
    __shared__ int csr_l[CAP];     // 40 KB
    __shared__ int ldeg[768];
    __shared__ int lrow[768];
    __shared__ int part[256];
    int t = threadIdx.x;
    int b = blockIdx.x;
    int lo = bstart[b], hi = bstart[b + 1];
    int len = hi - lo;
    if (len > CAP) len = CAP;
    for (int i = t; i < len; i += 256) pk[i] = packed[lo + i];
    for (int i = t; i < 768; i += 256) ldeg[i] = 0;
    __syncthreads();
    for (int i = t; i < len; i += 256) atomicAdd(&ldeg[pk[i] & FPACK_MASK], 1);
    __syncthreads();
    int a0 = ldeg[t * 3], a1 = ldeg[t * 3 + 1], a2 = ldeg[t * 3 + 2];
    part[t] = a0 + a1 + a2;
    __syncthreads();
    for (int o = 1; o < 256; o <<= 1) {
        int xg = (t >= o) ? part[t - o] : 0;
        __syncthreads();
        part[t] += xg;
        __syncthreads();
    }
    int run = t ? part[t - 1] : 0;
    lrow[t * 3] = run;
    lrow[t * 3 + 1] = run + a0;
    lrow[t * 3 + 2] = run + a0 + a1;
    __syncthreads();
    int n0 = b * BUCKET_N;
    int nnode = NNODES - n0; if (nnode > BUCKET_N) nnode = BUCKET_N;
    for (int l = t; l < nnode; l += 256) {
        int dg = ldeg[l];
        int n = n0 + l;
        float di = rsqrtf((float)(dg + 1));
        deg[n] = dg;
        rowstart[n] = lo + lrow[l];
        dinv[n] = di;
        h8 o;
#pragma unroll
        for (int c = 0; c < 5; ++c) o.v[c] = (h16)(x[(unsigned)n * 5u + c] * di);
        o.v[5] = (h16)0.f; o.v[6] = (h16)0.f; o.v[7] = (h16)0.f;
        xs8h[n] = o;
    }
    for (int l = t; l < 768; l += 256) ldeg[l] = lrow[l];   // cursor
    __syncthreads();
    for (int i = t; i < len; i += 256) {
        unsigned v = pk[i];
        int pos = atomicAdd(&ldeg[v & FPACK_MASK], 1);
        csr_l[pos] = (int)(v >> FPACK_SHIFT);
    }
    __syncthreads();
    for (int i = t; i < len; i += 256) csr[lo + i] = csr_l[i];
}

// ================= GCN layers (fp16 gather operands, fp32 math) =================

// layer1 gather (node per lane) + fused mm1 + relu + mm2 + prescale -> g2sh (16 x fp16)
__global__ __launch_bounds__(256) void g8h_mm12(const int* __restrict__ rowstart,
                                                const int* __restrict__ deg,
                                                const int* __restrict__ csr,
                                                const h8* __restrict__ xs8h,
                                                const float* __restrict__ dinv,
                                                const float* __restrict__ W1,
                                                const float* __restrict__ b1,
                                                const float* __restrict__ W2,
                                                h8* __restrict__ g2sh) {
    __shared__ float W1s[5 * 32], W2s[32 * 16], b1s[32];
    int tid = threadIdx.x;
    if (tid < 5 * 32) W1s[tid] = W1[tid];
    if (tid < 32) b1s[tid] = b1[tid];
    for (int i = tid; i < 32 * 16; i += 256) W2s[i] = W2[i];
    __syncthreads();

    unsigned n = blockIdx.x * 256u + tid;
    if (n >= NNODES) return;
    int rs = rowstart[n], d = deg[n];
    float acc[8];
    {
        h8 s = xs8h[n];
#pragma unroll
        for (int k = 0; k < 8; ++k) acc[k] = (float)s.v[k];
    }
    int j = 0;
    for (; j + 2 <= d; j += 2) {
        int s0 = csr[rs + j], s1 = csr[rs + j + 1];
        h8 a = xs8h[s0], bb = xs8h[s1];
#pragma unroll
        for (int k = 0; k < 8; ++k) acc[k] += (float)a.v[k] + (float)bb.v[k];
    }
    for (; j < d; ++j) {
        h8 a = xs8h[csr[rs + j]];
#pragma unroll
        for (int k = 0; k < 8; ++k) acc[k] += (float)a.v[k];
    }
    float di = dinv[n];
    float a5[5];
#pragma unroll
    for (int k = 0; k < 5; ++k) a5[k] = acc[k] * di;
    float g[16];
#pragma unroll
    for (int c = 0; c < 16; ++c) g[c] = 0.f;
#pragma unroll
    for (int jj = 0; jj < 32; ++jj) {
        float hv = b1s[jj];
#pragma unroll
        for (int k = 0; k < 5; ++k) hv += a5[k] * W1s[k * 32 + jj];
        hv = hv > 0.f ? hv : 0.f;
#pragma unroll
        for (int c = 0; c < 16; ++c) g[c] += hv * W2s[jj * 16 + c];
    }
    h8 o0, o1;
#pragma unroll
    for (int c = 0; c < 8; ++c) {
        o0.v[c] = (h16)(g[c] * di);
        o1.v[c] = (h16)(g[c + 8] * di);
    }
    g2sh[n * 2u] = o0;
    g2sh[n * 2u + 1] = o1;
}

// layer2 gather (2 lanes per node, 8ch each) + relu + mm3 + prescale -> g3s4h (4 x fp16)
__global__ __launch_bounds__(256) void g16h_mm3(const int* __restrict__ rowstart,
                                                const int* __restrict__ deg,
                                                const int* __restrict__ csr,
                                                const h8* __restrict__ g2sh,
                                                const float* __restrict__ dinv,
                                                const float* __restrict__ b2,
                                                const float* __restrict__ W3,
                                                h4* __restrict__ g3s4h) {
    __shared__ float W3s[16 * 3], b2s[16];
    int tid = threadIdx.x;
    if (tid < 16 * 3) W3s[tid] = W3[tid];
    if (tid < 16) b2s[tid] = b2[tid];
    __syncthreads();
    unsigned t = blockIdx.x * 256u + tid;
    unsigned g = t >> 1, c = t & 1u;
    if (g >= NNODES) return;
    int rs = rowstart[g], d = deg[g];
    float acc[8];
    {
        h8 s = g2sh[g * 2u + c];
#pragma unroll
        for (int k = 0; k < 8; ++k) acc[k] = (float)s.v[k];
    }
    int j = 0;
    for (; j + 2 <= d; j += 2) {
        int s0 = csr[rs + j], s1 = csr[rs + j + 1];
        h8 a = g2sh[(unsigned)s0 * 2u + c], bb = g2sh[(unsigned)s1 * 2u + c];
#pragma unroll
        for (int k = 0; k < 8; ++k) acc[k] += (float)a.v[k] + (float)bb.v[k];
    }
    for (; j < d; ++j) {
        h8 a = g2sh[(unsigned)csr[rs + j] * 2u + c];
#pragma unroll
        for (int k = 0; k < 8; ++k) acc[k] += (float)a.v[k];
    }
    float di = dinv[g];
    float p0 = 0.f, p1 = 0.f, p2 = 0.f;
#pragma unroll
    for (int jj = 0; jj < 8; ++jj) {
        int ch = c * 8 + jj;
        float v = acc[jj] * di + b2s[ch];
        v = v > 0.f ? v : 0.f;
        p0 += v * W3s[ch * 3 + 0];
        p1 += v * W3s[ch * 3 + 1];
        p2 += v * W3s[ch * 3 + 2];
    }
    p0 += __shfl_xor(p0, 1);
    p1 += __shfl_xor(p1, 1);
    p2 += __shfl_xor(p2, 1);
    if (c == 0) {
        h4 o;
        o.v[0] = (h16)(p0 * di);
        o.v[1] = (h16)(p1 * di);
        o.v[2] = (h16)(p2 * di);
        o.v[3] = (h16)0.f;
        g3s4h[g] = o;
    }
}

// layer3 gather (node per lane) + bias + relu -> h3 fp32
__global__ __launch_bounds__(256) void g4h_final(const int* __restrict__ rowstart,
                                                 const int* __restrict__ deg,
                                                 const int* __restrict__ csr,
                                                 const h4* __restrict__ g3,
                                                 const float* __restrict__ dinv,
                                                 const float* __restrict__ b3,
                                                 float* __restrict__ h3) {
    unsigned g = blockIdx.x * 256u + threadIdx.x;
    if (g >= NNODES) return;
    int rs = rowstart[g], d = deg[g];
    float a0, a1, a2;
    {
        h4 s = g3[g];
        a0 = (float)s.v[0]; a1 = (float)s.v[1]; a2 = (float)s.v[2];
    }
    int j = 0;
    for (; j + 2 <= d; j += 2) {
        h4 v0 = g3[csr[rs + j]], v1 = g3[csr[rs + j + 1]];
        a0 += (float)v0.v[0] + (float)v1.v[0];
        a1 += (float)v0.v[1] + (float)v1.v[1];
        a2 += (float)v0.v[2] + (float)v1.v[2];
    }
    for (; j < d; ++j) {
        h4 v = g3[csr[rs + j]];
        a0 += (float)v.v[0]; a1 += (float)v.v[1]; a2 += (float)v.v[2];
    }
    float di = dinv[g];
    float o0 = a0 * di + b3[0];
    float o1 = a1 * di + b3[1];
    float o2 = a2 * di + b3[2];
    h3[g * 3u + 0] = o0 > 0.f ? o0 : 0.f;
    h3[g * 3u + 1] = o1 > 0.f ? o1 : 0.f;
    h3[g * 3u + 2] = o2 > 0.f ? o2 : 0.f;
}

// ================= head =================

// block = (seg, batch-group of 4); Wl1 segment staged once in LDS
__global__ __launch_bounds__(256) void k_head3(const float* __restrict__ h3,
                                               const float* __restrict__ Wl1,
                                               float* __restrict__ zpart) {
    __shared__ float Wl1s[SEGK * 32];   // 28 KB
    __shared__ float hrow[SEGK];
    __shared__ float part[8][32];
    int seg = blockIdx.x & 31, bg = blockIdx.x >> 5;
    int tid = threadIdx.x;
    int k0 = seg * SEGK;
    int cnt = HEADK - k0; if (cnt > SEGK) cnt = SEGK;
    for (int i = tid; i < cnt * 32; i += 256) Wl1s[i] = Wl1[k0 * 32 + i];
    int j = tid & 31, kg = tid >> 5;
    for (int bb = 0; bb < BPB; ++bb) {
        int b = bg * BPB + bb;
        __syncthreads();
        for (int k = tid; k < cnt; k += 256) hrow[k] = h3[b * HEADK + k0 + k];
        __syncthreads();
        float acc = 0.f;
        for (int k = kg; k < cnt; k += 8) acc += hrow[k] * Wl1s[k * 32 + j];
        part[kg][j] = acc;
        __syncthreads();
        if (tid < 32) {
            float s = 0.f;
#pragma unroll
            for (int g2 = 0; g2 < 8; ++g2) s += part[g2][tid];
            zpart[(seg * NB + b) * 32 + tid] = s;
        }
    }
}

__global__ void k_bn_final(const float* __restrict__ zpart, const float* __restrict__ bl1,
                           const float* __restrict__ gamma, const float* __restrict__ beta,
                           const float* __restrict__ Wl2, const float* __restrict__ bl2,
                           float* __restrict__ out) {
    __shared__ float zs[NB][32];
    __shared__ float scale[32], shift[32];
    int tid = threadIdx.x;  // 256
    for (int i = tid; i < NB * 32; i += 256) {
        float v = bl1[i & 31];
#pragma unroll
        for (int sgm = 0; sgm < HEAD_SEG; ++sgm) v += zpart[sgm * NB * 32 + i];
        zs[i >> 5][i & 31] = v;
    }
    __syncthreads();
    if (tid < 32) {
        float m = 0.f, v = 0.f;
        for (int b = 0; b < NB; ++b) { float xv = zs[b][tid]; m += xv; v += xv * xv; }
        m /= (float)NB;
        v = v / (float)NB - m * m;
        float sc = gamma[tid] * rsqrtf(v + BN_EPS);
        scale[tid] = sc;
        shift[tid] = beta[tid] - m * sc;
    }
    __syncthreads();
    if (tid < NB) {
        float acc = bl2[0];
#pragma unroll
        for (int j = 0; j < 32; ++j) {
            float zv = zs[tid][j] * scale[j] + shift[j];
            zv = zv > 0.f ? zv : 0.f;
            acc += zv * Wl2[j];
        }
        out[tid] = acc;
    }
}

// ================= launch =================

extern "C" void kernel_launch(void* const* d_in, const int* in_sizes, int n_in,
                              void* d_out, int out_size, void* d_ws, size_t ws_size,
                              hipStream_t stream) {
    const float* x    = (const float*)d_in[0];
    const int*   ei   = (const int*)d_in[1];
    const float* W1   = (const float*)d_in[2];
    const float* b1   = (const float*)d_in[3];
    const float* W2   = (const float*)d_in[4];
    const float* b2   = (const float*)d_in[5];
    const float* W3   = (const float*)d_in[6];
    const float* b3   = (const float*)d_in[7];
    const float* Wl1  = (const float*)d_in[8];
    const float* bl1  = (const float*)d_in[9];
    const float* gamma= (const float*)d_in[10];
    const float* beta = (const float*)d_in[11];
    const float* Wl2  = (const float*)d_in[12];
    const float* bl2  = (const float*)d_in[13];

    const int* src = ei;            // edge_index[0]
    const int* dst = ei + NEDGES;   // edge_index[1]

    char* ws = (char*)d_ws;
    size_t off = 0;
    float*    dinv     = (float*)   (ws + off); off += (size_t)NNODES * 4;
    int*      deg      = (int*)     (ws + off); off += (size_t)NNODES * 4;
    int*      counts   = (int*)     (ws + off); off += (size_t)NBUCK * NCHUNK * 4;
    int*      bases    = (int*)     (ws + off); off += (size_t)NBUCK * NCHUNK * 4;
    int*      btot     = (int*)     (ws + off); off += (size_t)NBUCK * 4;
    int*      bstart   = (int*)     (ws + off); off += (size_t)(NBUCK + 1) * 4;
    off = (off + 255) & ~(size_t)255;
    unsigned* packed   = (unsigned*)(ws + off); off += (size_t)NEDGES * 4;
    int*      rowstart = (int*)     (ws + off); off += (size_t)NNODES * 4;
    int*      csr      = (int*)     (ws + off); off += (size_t)NEDGES * 4;
    h8*       xs8h     = (h8*)      (ws + off); off += (size_t)NNODES * 16;
    h8*       g2sh     = (h8*)      (ws + off); off += (size_t)NNODES * 32;
    h4*       g3s4h    = (h4*)      (ws + off); off += (size_t)NNODES * 8;
    float*    h3       = (float*)   (ws + off); off += (size_t)NNODES * 3 * 4;
    float*    zpart    = (float*)   (ws + off); off += (size_t)HEAD_SEG * NB * 32 * 4;

    float* outp = (float*)d_out;

    // ---- CSR build (all global stores coalesced; scatter staged in LDS) + fused x*dinv fp16 pack
    k_count<<<NCHUNK, 256, 0, stream>>>(dst, counts);
    k_scanA<<<NBUCK, 256, 0, stream>>>(counts, bases, btot);
    k_scanB<<<1, 256, 0, stream>>>(btot, bstart);
    k_bin_sorted<<<NCHUNK, 256, 0, stream>>>(src, dst, bases, bstart, packed);
    k_build<<<NBUCK, 256, 0, stream>>>(packed, bstart, x, deg, rowstart, dinv, csr, xs8h);

    // ---- layer1 gather + mm1 + relu + mm2 + prescale
    g8h_mm12<<<(NNODES + 255) / 256, 256, 0, stream>>>(
        rowstart, deg, csr, xs8h, dinv, W1, b1, W2, g2sh);

    // ---- layer2 gather + relu + mm3 + prescale
    g16h_mm3<<<(int)(((unsigned)NNODES * 2u + 255) / 256), 256, 0, stream>>>(
        rowstart, deg, csr, g2sh, dinv, b2, W3, g3s4h);

    // ---- layer3 gather + bias + relu
    g4h_final<<<(NNODES + 255) / 256, 256, 0, stream>>>(
        rowstart, deg, csr, g3s4h, dinv, b3, h3);

    // ---- head + BN + final linear
    k_head3<<<HEAD_SEG * BGRP, 256, 0, stream>>>(h3, Wl1, zpart);
    k_bn_final<<<1, 256, 0, stream>>>(zpart, bl1, gamma, beta, Wl2, bl2, outp);
}